// Round 8
// baseline (3758.505 us; speedup 1.0000x reference)
//
#include <hip/hip_runtime.h>
#include <hip/hip_bf16.h>

#define T_TOK 4096
#define HD 1024
#define ID 2048
#define NE 8

typedef __attribute__((ext_vector_type(8))) __bf16 bf16x8;
typedef __attribute__((ext_vector_type(4))) float f32x4;
typedef __attribute__((ext_vector_type(4))) unsigned int u32x4;
typedef __attribute__((ext_vector_type(2))) unsigned int u32x2;

#define AS1 __attribute__((address_space(1)))
#define AS3 __attribute__((address_space(3)))

#define WAITV(N) asm volatile("s_waitcnt vmcnt(" #N ")" ::: "memory")
#define BAR()    asm volatile("s_barrier" ::: "memory")
#define LGKM0()  { asm volatile("s_waitcnt lgkmcnt(0)" ::: "memory"); __builtin_amdgcn_sched_barrier(0); }

__device__ __forceinline__ unsigned short f2bf(float f) {
  __hip_bfloat16 h = __float2bfloat16(f);
  return __builtin_bit_cast(unsigned short, h);
}
__device__ __forceinline__ unsigned int pk2(float lo, float hi) {
  return (unsigned int)f2bf(lo) | ((unsigned int)f2bf(hi) << 16);
}
__device__ __forceinline__ float bflo(unsigned int u) { return __builtin_bit_cast(float, u << 16); }
__device__ __forceinline__ float bfhi(unsigned int u) { return __builtin_bit_cast(float, u & 0xffff0000u); }
__device__ __forceinline__ void gl16(const void* g, void* l) {
  __builtin_amdgcn_global_load_lds((const AS1 unsigned int*)g, (AS3 unsigned int*)l, 16, 0, 0);
}

// ---------------- routing ----------------
__global__ void k_zero(int* cnt) { if (threadIdx.x < 32) cnt[threadIdx.x] = 0; }

__global__ __launch_bounds__(256) void k_route(const float* __restrict__ x,
    const float* __restrict__ gw, const float* __restrict__ bias,
    int* __restrict__ cnt, int* __restrict__ tokens, float* __restrict__ wts,
    int* __restrict__ slotrec)
{
  const int lane = threadIdx.x & 63;
  const int t = blockIdx.x * 4 + (threadIdx.x >> 6);
  const float* xr = x + (size_t)t * HD + lane * 16;
  f32x4 xv[4];
  #pragma unroll
  for (int j = 0; j < 4; ++j) xv[j] = *(const f32x4*)(xr + j * 4);
  float sc[NE];
  #pragma unroll
  for (int e = 0; e < NE; ++e) {
    const float* gr = gw + e * HD + lane * 16;
    float a = 0.f;
    #pragma unroll
    for (int j = 0; j < 4; ++j) {
      f32x4 gv = *(const f32x4*)(gr + j * 4);
      a += xv[j][0]*gv[0] + xv[j][1]*gv[1] + xv[j][2]*gv[2] + xv[j][3]*gv[3];
    }
    #pragma unroll
    for (int off = 32; off > 0; off >>= 1) a += __shfl_xor(a, off);
    sc[e] = a;
  }
  int i1 = 0; float b1 = sc[0] + bias[0];
  #pragma unroll
  for (int e = 1; e < NE; ++e) { float be = sc[e] + bias[e]; if (be > b1) { b1 = be; i1 = e; } }
  int i2 = -1; float b2 = -3e38f;
  #pragma unroll
  for (int e = 0; e < NE; ++e) { if (e == i1) continue; float be = sc[e] + bias[e]; if (be > b2) { b2 = be; i2 = e; } }
  int a1 = 0; float r1 = sc[0];
  #pragma unroll
  for (int e = 1; e < NE; ++e) if (sc[e] > r1) { r1 = sc[e]; a1 = e; }
  float r2 = -3e38f;
  #pragma unroll
  for (int e = 0; e < NE; ++e) if (e != a1 && sc[e] > r2) r2 = sc[e];
  float w1 = 1.f / (1.f + __expf(-r1));
  float w2 = 1.f / (1.f + __expf(-r2));
  float s = w1 + w2; w1 /= s; w2 /= s;
  if (lane == 0) {
    int p = atomicAdd(&cnt[i1], 1); tokens[i1 * T_TOK + p] = t; wts[i1 * T_TOK + p] = w1;
    slotrec[t * 2] = (i1 << 16) | p;
    p = atomicAdd(&cnt[i2], 1);     tokens[i2 * T_TOK + p] = t; wts[i2 * T_TOK + p] = w2;
    slotrec[t * 2 + 1] = (i2 << 16) | p;
  }
}

__global__ void k_fin(const int* __restrict__ cnt, int* __restrict__ base, float* __restrict__ out)
{
  if (threadIdx.x == 0) {
    int b = 0, mx = 0;
    #pragma unroll
    for (int e = 0; e < NE; ++e) { base[e] = b; b += cnt[e]; if (cnt[e] > mx) mx = cnt[e]; }
    base[NE] = b;
    out[(size_t)T_TOK * HD] = (float)mx * (1.f / 1024.f) - 1.f;  // viol
  }
}

// ---------------- converts ----------------
__global__ __launch_bounds__(256) void k_cvtx(const float* __restrict__ x, unsigned short* __restrict__ xb) {
  size_t i = ((size_t)blockIdx.x * 256 + threadIdx.x) * 8;
  f32x4 v0 = *(const f32x4*)(x + i), v1 = *(const f32x4*)(x + i + 4);
  u32x4 pk = { pk2(v0[0],v0[1]), pk2(v0[2],v0[3]), pk2(v1[0],v1[1]), pk2(v1[2],v1[3]) };
  *(u32x4*)&xb[i] = pk;
}

#define TCVT_BODY(src, dst, K, N, mode) { \
  const int k0 = blockIdx.y * 64, n0 = blockIdx.x * 64; \
  const int t = threadIdx.x; \
  const int nc = (t & 15) * 4; \
  _Pragma("unroll") \
  for (int it = 0; it < 4; ++it) { \
    int kr = (t >> 4) + it * 16; \
    f32x4 v = *(const f32x4*)&src[(size_t)(k0 + kr) * N + n0 + nc]; \
    _Pragma("unroll") \
    for (int j = 0; j < 4; ++j) { \
      int n = nc + j; \
      tl[n * 64 + (((kr >> 3) ^ (n & 7)) * 8) + (kr & 7)] = f2bf(v[j]); \
    } \
  } \
  __syncthreads(); \
  _Pragma("unroll") \
  for (int it = 0; it < 2; ++it) { \
    int idx = t + it * 256; \
    int n = idx >> 3, kc8 = idx & 7; \
    u32x4 v = *(const u32x4*)&tl[n * 64 + ((kc8 ^ (n & 7)) * 8)]; \
    int nn = n0 + n; \
    int vrow = ((mode) == 0) ? nn : (((nn >> 5) << 6) + (nn & 31) + (((mode) == 2) ? 32 : 0)); \
    *(u32x4*)&dst[(size_t)vrow * K + k0 + kc8 * 8] = v; \
  } }

__global__ __launch_bounds__(256) void k_tcvtA(const float* __restrict__ Wg, const float* __restrict__ Wu,
    const float* __restrict__ Sg, const float* __restrict__ Su,
    unsigned short* __restrict__ Wgu, unsigned short* __restrict__ Sgu)
{
  __shared__ __attribute__((aligned(16))) unsigned short tl[64 * 64];
  const int z = blockIdx.z;
  const float* src; unsigned short* dst; int mode;
  if (z < 8)        { src = Wg + (size_t)z * HD * ID;       dst = Wgu + (size_t)z * 4096 * 1024; mode = 1; }
  else if (z < 16)  { src = Wu + (size_t)(z - 8) * HD * ID; dst = Wgu + (size_t)(z - 8) * 4096 * 1024; mode = 2; }
  else if (z == 16) { src = Sg; dst = Sgu; mode = 1; }
  else              { src = Su; dst = Sgu; mode = 2; }
  TCVT_BODY(src, dst, HD, ID, mode)
}

__global__ __launch_bounds__(256) void k_tcvtB(const float* __restrict__ Wd, const float* __restrict__ Sd,
    unsigned short* __restrict__ WdT, unsigned short* __restrict__ SdT)
{
  __shared__ __attribute__((aligned(16))) unsigned short tl[64 * 64];
  const int z = blockIdx.z;
  const float* src = (z < 8) ? Wd + (size_t)z * ID * HD : Sd;
  unsigned short* dst = (z < 8) ? WdT + (size_t)z * ID * HD : SdT;
  TCVT_BODY(src, dst, ID, HD, 0)
}

// ================= GEMM1: 256x256 virtual, BK=32, 2 slots, 64KB LDS (2 blocks/CU) =================
// LDS A/B [256 rows][32 k] bf16; chunk p of row r holds k-group p ^ ((r>>1)&3).
__global__ __launch_bounds__(512, 4) void k_mlp1(
    const unsigned short* __restrict__ xb,
    const unsigned short* __restrict__ Wgu, const unsigned short* __restrict__ Sgu,
    const int* __restrict__ cnt, const int* __restrict__ base, const int* __restrict__ tokens,
    unsigned short* __restrict__ act)
{
  __shared__ __attribute__((aligned(16))) unsigned short Abuf[2][8192];
  __shared__ __attribute__((aligned(16))) unsigned short Bbuf[2][8192];

  // bijective XCD-chunked swizzle over 2304 = 8 x 288 blocks; n-panel-major within chunk
  const int g = (blockIdx.x & 7) * 288 + (blockIdx.x >> 3);
  const int e = g >> 8;
  const int r_ = g & 255;
  const int nx = r_ & 15, my = r_ >> 4;
  const int cntE = (e == NE) ? T_TOK : cnt[e];
  const int m0 = my * 256;
  if (m0 >= cntE) return;
  const int n0 = nx * 256;                               // virtual col base
  const unsigned short* Bsrc = (e == NE) ? Sgu : Wgu + (size_t)e * 4096 * 1024;
  const int rowbase = (e == NE) ? 2 * T_TOK : base[e];
  const int tid = threadIdx.x, lane = tid & 63, w = tid >> 6;

  // staging: gl16 j of wave w covers rows (j*8+w)*16 .. +15; lane l -> row +(l>>2), chunk (l&3)
  const unsigned short* asp[2]; const unsigned short* bsp[2];
  #pragma unroll
  for (int j = 0; j < 2; ++j) {
    int R = (j * 8 + w) * 16 + (lane >> 2);
    int kc = (lane & 3) ^ ((R >> 1) & 3);
    int rl = min(m0 + R, cntE - 1);
    int tok = (e == NE) ? rl : tokens[e * T_TOK + rl];
    asp[j] = xb + (size_t)tok * HD + kc * 8;
    bsp[j] = Bsrc + (size_t)(n0 + R) * HD + kc * 8;
  }

  f32x4 acc[8][4];
  const f32x4 z4 = {0.f, 0.f, 0.f, 0.f};
  #pragma unroll
  for (int i = 0; i < 8; ++i)
    #pragma unroll
    for (int j = 0; j < 4; ++j) acc[i][j] = z4;

  const int lr = lane & 15, lg = lane >> 4;
  const int wm = (w >> 2) * 128;                         // 2 M-wave groups x 128 rows
  const int wn4 = (w & 3) * 64;                          // 4 N-waves x 64 virtual cols
  int abyte[8], bbyte[4];
  #pragma unroll
  for (int am = 0; am < 8; ++am) { int rr = wm + am * 16 + lr;  abyte[am] = rr * 64 + ((lg ^ ((rr >> 1) & 3)) * 16); }
  #pragma unroll
  for (int bn = 0; bn < 4; ++bn) { int rr = wn4 + bn * 16 + lr; bbyte[bn] = rr * 64 + ((lg ^ ((rr >> 1) & 3)) * 16); }

  bf16x8 af[8], bfr[4];

  #define STAGE1(t_, s_) { \
    gl16(asp[0] + (t_) * 32, &Abuf[s_][w * 512]); \
    gl16(asp[1] + (t_) * 32, &Abuf[s_][4096 + w * 512]); \
    gl16(bsp[0] + (t_) * 32, &Bbuf[s_][w * 512]); \
    gl16(bsp[1] + (t_) * 32, &Bbuf[s_][4096 + w * 512]); \
    __builtin_amdgcn_sched_barrier(0); }
  #define LD1(s_) { \
    _Pragma("unroll") for (int am_ = 0; am_ < 8; ++am_) af[am_]  = *(const bf16x8*)((const char*)&Abuf[s_][0] + abyte[am_]); \
    _Pragma("unroll") for (int bn_ = 0; bn_ < 4; ++bn_) bfr[bn_] = *(const bf16x8*)((const char*)&Bbuf[s_][0] + bbyte[bn_]); }
  #define MM() { __builtin_amdgcn_s_setprio(1); \
    _Pragma("unroll") for (int bn_ = 0; bn_ < 4; ++bn_) \
      _Pragma("unroll") for (int am_ = 0; am_ < 8; ++am_) \
        acc[am_][bn_] = __builtin_amdgcn_mfma_f32_16x16x32_bf16(af[am_], bfr[bn_], acc[am_][bn_], 0, 0, 0); \
    __builtin_amdgcn_s_setprio(0); }

  const int NT = 32;  // K=1024 / 32
  STAGE1(0, 0); STAGE1(1, 1);
  WAITV(4);
  BAR();
  for (int t = 0; t < NT; t += 2) {
    LD1(0); LGKM0(); BAR();
    if (t + 2 < NT) STAGE1(t + 2, 0);
    MM();
    if (t + 2 < NT) { WAITV(4); } else { WAITV(0); }
    BAR();
    LD1(1); LGKM0(); BAR();
    if (t + 3 < NT) STAGE1(t + 3, 1);
    MM();
    if (t + 3 < NT) { WAITV(4); } else { WAITV(0); }
    BAR();
  }
  #undef STAGE1
  #undef LD1
  #undef MM

  // epilogue: gate frags (bn 0,1) pair with up frags (bn 2,3)
  const int colbase = ((n0 + wn4) >> 1);
  #pragma unroll
  for (int am = 0; am < 8; ++am) {
    const int rloc = wm + am * 16 + lg * 4;
    #pragma unroll
    for (int p = 0; p < 2; ++p) {
      f32x4 gv = acc[am][p], uv = acc[am][p + 2];
      int col = colbase + p * 16 + lr;
      #pragma unroll
      for (int q = 0; q < 4; ++q) {
        int r = rloc + q;
        if (m0 + r < cntE) {
          float gg = gv[q], uu = uv[q];
          act[(size_t)(rowbase + m0 + r) * ID + col] = f2bf((gg / (1.f + __expf(-gg))) * uu);
        }
      }
    }
  }
}

// ================= GEMM2: 256x256, split-K=2, BK=32, 2 slots, 64KB LDS =================
__global__ __launch_bounds__(512, 4) void k_mlp2(
    const unsigned short* __restrict__ act,
    const unsigned short* __restrict__ WdT, const unsigned short* __restrict__ SdT,
    const int* __restrict__ cnt, const int* __restrict__ base,
    unsigned short* __restrict__ dn0, unsigned short* __restrict__ dn1)
{
  __shared__ __attribute__((aligned(16))) unsigned short Abuf[2][8192];
  __shared__ __attribute__((aligned(16))) unsigned short Bbuf[2][8192];

  // bijective XCD swizzle over 1152 = 8 x 144; n-panel-major within chunk
  const int g = (blockIdx.x & 7) * 144 + (blockIdx.x >> 3);
  const int z = g >> 6;
  const int r_ = g & 63;
  const int nx = r_ & 3, my = r_ >> 2;
  const int e = z >> 1, kh = z & 1;
  const int cntE = (e == NE) ? T_TOK : cnt[e];
  const int m0 = my * 256;
  if (m0 >= cntE) return;
  const int n0 = nx * 256;
  const unsigned short* Bsrc = (e == NE) ? SdT : WdT + (size_t)e * ID * HD;
  const int rowbase = (e == NE) ? 2 * T_TOK : base[e];
  const int koff = kh * 1024;
  const int tid = threadIdx.x, lane = tid & 63, w = tid >> 6;

  const unsigned short* asp[2]; const unsigned short* bsp[2];
  #pragma unroll
  for (int j = 0; j < 2; ++j) {
    int R = (j * 8 + w) * 16 + (lane >> 2);
    int kc = (lane & 3) ^ ((R >> 1) & 3);
    int rl = rowbase + min(m0 + R, cntE - 1);
    asp[j] = act + (size_t)rl * ID + koff + kc * 8;
    bsp[j] = Bsrc + (size_t)(n0 + R) * ID + koff + kc * 8;
  }

  f32x4 acc[8][4];
  const f32x4 z4 = {0.f, 0.f, 0.f, 0.f};
  #pragma unroll
  for (int i = 0; i < 8; ++i)
    #pragma unroll
    for (int j = 0; j < 4; ++j) acc[i][j] = z4;

  const int lr = lane & 15, lg = lane >> 4;
  const int wm = (w >> 2) * 128;
  const int wn4 = (w & 3) * 64;
  int abyte[8], bbyte[4];
  #pragma unroll
  for (int am = 0; am < 8; ++am) { int rr = wm + am * 16 + lr;  abyte[am] = rr * 64 + ((lg ^ ((rr >> 1) & 3)) * 16); }
  #pragma unroll
  for (int bn = 0; bn < 4; ++bn) { int rr = wn4 + bn * 16 + lr; bbyte[bn] = rr * 64 + ((lg ^ ((rr >> 1) & 3)) * 16); }

  bf16x8 af[8], bfr[4];

  #define STAGE2(t_, s_) { \
    gl16(asp[0] + (t_) * 32, &Abuf[s_][w * 512]); \
    gl16(asp[1] + (t_) * 32, &Abuf[s_][4096 + w * 512]); \
    gl16(bsp[0] + (t_) * 32, &Bbuf[s_][w * 512]); \
    gl16(bsp[1] + (t_) * 32, &Bbuf[s_][4096 + w * 512]); \
    __builtin_amdgcn_sched_barrier(0); }
  #define LD2(s_) { \
    _Pragma("unroll") for (int am_ = 0; am_ < 8; ++am_) af[am_]  = *(const bf16x8*)((const char*)&Abuf[s_][0] + abyte[am_]); \
    _Pragma("unroll") for (int bn_ = 0; bn_ < 4; ++bn_) bfr[bn_] = *(const bf16x8*)((const char*)&Bbuf[s_][0] + bbyte[bn_]); }
  #define MM2() { __builtin_amdgcn_s_setprio(1); \
    _Pragma("unroll") for (int bn_ = 0; bn_ < 4; ++bn_) \
      _Pragma("unroll") for (int am_ = 0; am_ < 8; ++am_) \
        acc[am_][bn_] = __builtin_amdgcn_mfma_f32_16x16x32_bf16(af[am_], bfr[bn_], acc[am_][bn_], 0, 0, 0); \
    __builtin_amdgcn_s_setprio(0); }

  const int NT = 32;  // 1024 / 32 per K-half
  STAGE2(0, 0); STAGE2(1, 1);
  WAITV(4);
  BAR();
  for (int t = 0; t < NT; t += 2) {
    LD2(0); LGKM0(); BAR();
    if (t + 2 < NT) STAGE2(t + 2, 0);
    MM2();
    if (t + 2 < NT) { WAITV(4); } else { WAITV(0); }
    BAR();
    LD2(1); LGKM0(); BAR();
    if (t + 3 < NT) STAGE2(t + 3, 1);
    MM2();
    if (t + 3 < NT) { WAITV(4); } else { WAITV(0); }
    BAR();
  }
  #undef STAGE2
  #undef LD2
  #undef MM2

  unsigned short* dnp = kh ? dn1 : dn0;
  #pragma unroll
  for (int am = 0; am < 8; ++am) {
    const int rloc = wm + am * 16 + lg * 4;
    #pragma unroll
    for (int bn = 0; bn < 4; ++bn) {
      f32x4 av = acc[am][bn];
      int col = n0 + wn4 + bn * 16 + lr;
      #pragma unroll
      for (int q = 0; q < 4; ++q) {
        int r = rloc + q;
        if (m0 + r < cntE)
          dnp[(size_t)(rowbase + m0 + r) * HD + col] = f2bf(av[q]);
      }
    }
  }
}

// ---------------- combine ----------------
__global__ __launch_bounds__(256) void k_comb(const unsigned short* __restrict__ dn0,
    const unsigned short* __restrict__ dn1,
    const int* __restrict__ base, const int* __restrict__ slotrec,
    const float* __restrict__ wts, float* __restrict__ out)
{
  const int t = blockIdx.x;
  const int c = threadIdx.x * 4;
  int r0 = slotrec[t * 2], r1 = slotrec[t * 2 + 1];
  int e0 = r0 >> 16, p0 = r0 & 0xffff;
  int e1 = r1 >> 16, p1 = r1 & 0xffff;
  size_t s0 = (size_t)(base[e0] + p0) * HD + c;
  size_t s1 = (size_t)(base[e1] + p1) * HD + c;
  size_t sh = (size_t)(2 * T_TOK + t) * HD + c;
  float w0 = wts[e0 * T_TOK + p0], w1 = wts[e1 * T_TOK + p1];
  u32x2 vs0 = *(const u32x2*)&dn0[sh], vs1 = *(const u32x2*)&dn1[sh];
  u32x2 va0 = *(const u32x2*)&dn0[s0], va1 = *(const u32x2*)&dn1[s0];
  u32x2 vb0 = *(const u32x2*)&dn0[s1], vb1 = *(const u32x2*)&dn1[s1];
  f32x4 o;
  o[0] = (bflo(vs0[0]) + bflo(vs1[0])) + w0 * (bflo(va0[0]) + bflo(va1[0])) + w1 * (bflo(vb0[0]) + bflo(vb1[0]));
  o[1] = (bfhi(vs0[0]) + bfhi(vs1[0])) + w0 * (bfhi(va0[0]) + bfhi(va1[0])) + w1 * (bfhi(vb0[0]) + bfhi(vb1[0]));
  o[2] = (bflo(vs0[1]) + bflo(vs1[1])) + w0 * (bflo(va0[1]) + bflo(va1[1])) + w1 * (bflo(vb0[1]) + bflo(vb1[1]));
  o[3] = (bfhi(vs0[1]) + bfhi(vs1[1])) + w0 * (bfhi(va0[1]) + bfhi(va1[1])) + w1 * (bfhi(vb0[1]) + bfhi(vb1[1]));
  *(f32x4*)&out[(size_t)t * HD + c] = o;
}

extern "C" void kernel_launch(void* const* d_in, const int* in_sizes, int n_in,
                              void* d_out, int out_size, void* d_ws, size_t ws_size,
                              hipStream_t stream)
{
  const float* x    = (const float*)d_in[0];
  const float* gw   = (const float*)d_in[1];
  const float* bias = (const float*)d_in[2];
  const float* Wg   = (const float*)d_in[3];
  const float* Wu   = (const float*)d_in[4];
  const float* Wd   = (const float*)d_in[5];
  const float* Sg   = (const float*)d_in[6];
  const float* Su   = (const float*)d_in[7];
  const float* Sd   = (const float*)d_in[8];
  float* out = (float*)d_out;
  char* ws = (char*)d_ws;

  int*   cnt     = (int*)ws;
  int*   base    = cnt + 16;
  int*   tokens  = (int*)(ws + 512);
  float* wts     = (float*)(ws + 512 + (NE * T_TOK * 4));
  int*   slotrec = (int*)(ws + 512 + 2 * (NE * T_TOK * 4));

  const size_t MB = (size_t)1 << 20;
  unsigned short* xbf = (unsigned short*)(ws + 1 * MB);    // 8 MB
  unsigned short* WdT = (unsigned short*)(ws + 9 * MB);    // 32 MB
  unsigned short* SdT = (unsigned short*)(ws + 41 * MB);   // 4 MB
  unsigned short* Wgu = (unsigned short*)(ws + 45 * MB);   // 64 MB (dead after mlp1)
  unsigned short* Sgu = (unsigned short*)(ws + 109 * MB);  // 8 MB (dead after mlp1)
  unsigned short* actb = (unsigned short*)(ws + 117 * MB); // 48 MB
  unsigned short* dn0 = (unsigned short*)(ws + 45 * MB);   // 24 MB, overlays Wgu
  unsigned short* dn1 = (unsigned short*)(ws + 69 * MB);   // 24 MB, overlays Wgu

  k_zero<<<dim3(1), dim3(64), 0, stream>>>(cnt);
  k_cvtx<<<dim3(T_TOK * HD / 2048), dim3(256), 0, stream>>>(x, xbf);
  k_tcvtA<<<dim3(32, 16, 18), dim3(256), 0, stream>>>(Wg, Wu, Sg, Su, Wgu, Sgu);
  k_tcvtB<<<dim3(16, 32, 9),  dim3(256), 0, stream>>>(Wd, Sd, WdT, SdT);
  k_route<<<dim3(T_TOK / 4), dim3(256), 0, stream>>>(x, gw, bias, cnt, tokens, wts, slotrec);
  k_fin<<<dim3(1), dim3(64), 0, stream>>>(cnt, base, out);
  k_mlp1<<<dim3(2304), dim3(512), 0, stream>>>(xbf, Wgu, Sgu, cnt, base, tokens, actb);
  k_mlp2<<<dim3(1152), dim3(512), 0, stream>>>(actb, WdT, SdT, cnt, base, dn0, dn1);
  k_comb<<<dim3(T_TOK), dim3(256), 0, stream>>>(dn0, dn1, base, slotrec, wts, out);
}

// Round 9
// 556.293 us; speedup vs baseline: 6.7563x; 6.7563x over previous
//
#include <hip/hip_runtime.h>
#include <hip/hip_bf16.h>

#define T_TOK 4096
#define HD 1024
#define ID 2048
#define NE 8

typedef __attribute__((ext_vector_type(8))) __bf16 bf16x8;
typedef __attribute__((ext_vector_type(4))) float f32x4;
typedef __attribute__((ext_vector_type(4))) unsigned int u32x4;
typedef __attribute__((ext_vector_type(2))) unsigned int u32x2;

#define AS1 __attribute__((address_space(1)))
#define AS3 __attribute__((address_space(3)))

#define WAITV(N) asm volatile("s_waitcnt vmcnt(" #N ")" ::: "memory")
#define BAR()    asm volatile("s_barrier" ::: "memory")
#define LGKM0()  { asm volatile("s_waitcnt lgkmcnt(0)" ::: "memory"); __builtin_amdgcn_sched_barrier(0); }

__device__ __forceinline__ unsigned short f2bf(float f) {
  __hip_bfloat16 h = __float2bfloat16(f);
  return __builtin_bit_cast(unsigned short, h);
}
__device__ __forceinline__ unsigned int pk2(float lo, float hi) {
  return (unsigned int)f2bf(lo) | ((unsigned int)f2bf(hi) << 16);
}
__device__ __forceinline__ float bflo(unsigned int u) { return __builtin_bit_cast(float, u << 16); }
__device__ __forceinline__ float bfhi(unsigned int u) { return __builtin_bit_cast(float, u & 0xffff0000u); }
__device__ __forceinline__ void gl16(const void* g, void* l) {
  __builtin_amdgcn_global_load_lds((const AS1 unsigned int*)g, (AS3 unsigned int*)l, 16, 0, 0);
}

// ---------------- routing ----------------
__global__ void k_zero(int* cnt) { if (threadIdx.x < 32) cnt[threadIdx.x] = 0; }

__global__ __launch_bounds__(256) void k_route(const float* __restrict__ x,
    const float* __restrict__ gw, const float* __restrict__ bias,
    int* __restrict__ cnt, int* __restrict__ tokens, float* __restrict__ wts,
    int* __restrict__ slotrec)
{
  const int lane = threadIdx.x & 63;
  const int t = blockIdx.x * 4 + (threadIdx.x >> 6);
  const float* xr = x + (size_t)t * HD + lane * 16;
  f32x4 xv[4];
  #pragma unroll
  for (int j = 0; j < 4; ++j) xv[j] = *(const f32x4*)(xr + j * 4);
  float sc[NE];
  #pragma unroll
  for (int e = 0; e < NE; ++e) {
    const float* gr = gw + e * HD + lane * 16;
    float a = 0.f;
    #pragma unroll
    for (int j = 0; j < 4; ++j) {
      f32x4 gv = *(const f32x4*)(gr + j * 4);
      a += xv[j][0]*gv[0] + xv[j][1]*gv[1] + xv[j][2]*gv[2] + xv[j][3]*gv[3];
    }
    #pragma unroll
    for (int off = 32; off > 0; off >>= 1) a += __shfl_xor(a, off);
    sc[e] = a;
  }
  int i1 = 0; float b1 = sc[0] + bias[0];
  #pragma unroll
  for (int e = 1; e < NE; ++e) { float be = sc[e] + bias[e]; if (be > b1) { b1 = be; i1 = e; } }
  int i2 = -1; float b2 = -3e38f;
  #pragma unroll
  for (int e = 0; e < NE; ++e) { if (e == i1) continue; float be = sc[e] + bias[e]; if (be > b2) { b2 = be; i2 = e; } }
  int a1 = 0; float r1 = sc[0];
  #pragma unroll
  for (int e = 1; e < NE; ++e) if (sc[e] > r1) { r1 = sc[e]; a1 = e; }
  float r2 = -3e38f;
  #pragma unroll
  for (int e = 0; e < NE; ++e) if (e != a1 && sc[e] > r2) r2 = sc[e];
  float w1 = 1.f / (1.f + __expf(-r1));
  float w2 = 1.f / (1.f + __expf(-r2));
  float s = w1 + w2; w1 /= s; w2 /= s;
  if (lane == 0) {
    int p = atomicAdd(&cnt[i1], 1); tokens[i1 * T_TOK + p] = t; wts[i1 * T_TOK + p] = w1;
    slotrec[t * 2] = (i1 << 16) | p;
    p = atomicAdd(&cnt[i2], 1);     tokens[i2 * T_TOK + p] = t; wts[i2 * T_TOK + p] = w2;
    slotrec[t * 2 + 1] = (i2 << 16) | p;
  }
}

__global__ void k_fin(const int* __restrict__ cnt, int* __restrict__ base, float* __restrict__ out)
{
  if (threadIdx.x == 0) {
    int b = 0, mx = 0;
    #pragma unroll
    for (int e = 0; e < NE; ++e) { base[e] = b; b += cnt[e]; if (cnt[e] > mx) mx = cnt[e]; }
    base[NE] = b;
    out[(size_t)T_TOK * HD] = (float)mx * (1.f / 1024.f) - 1.f;  // viol
  }
}

// ---------------- fused converts ----------------
// transpose-convert one 64x64 tile: src [K][N] fp32 -> dst [vmap(N)][K] bf16
__device__ __forceinline__ void tcvt_tile(const float* __restrict__ src, unsigned short* __restrict__ dst,
                                          int K, int N, int mode, int k0, int n0, unsigned short* tl)
{
  const int t = threadIdx.x;
  const int nc = (t & 15) * 4;
  #pragma unroll
  for (int it = 0; it < 4; ++it) {
    int kr = (t >> 4) + it * 16;
    f32x4 v = *(const f32x4*)&src[(size_t)(k0 + kr) * N + n0 + nc];
    #pragma unroll
    for (int j = 0; j < 4; ++j) {
      int n = nc + j;
      tl[n * 64 + (((kr >> 3) ^ (n & 7)) * 8) + (kr & 7)] = f2bf(v[j]);
    }
  }
  __syncthreads();
  #pragma unroll
  for (int it = 0; it < 2; ++it) {
    int idx = t + it * 256;
    int n = idx >> 3, kc8 = idx & 7;
    u32x4 v = *(const u32x4*)&tl[n * 64 + ((kc8 ^ (n & 7)) * 8)];
    int nn = n0 + n;
    int vrow = (mode == 0) ? nn : (((nn >> 5) << 6) + (nn & 31) + ((mode == 2) ? 32 : 0));
    *(u32x4*)&dst[(size_t)vrow * K + k0 + kc8 * 8] = v;
  }
}

// blocks 0..2047: x fp32->bf16; 2048..11263: Wg/Wu/Sg/Su -> Wgu/Sgu; 11264..15871: Wd/Sd -> WdT/SdT
__global__ __launch_bounds__(256) void k_conv(const float* __restrict__ x,
    const float* __restrict__ Wg, const float* __restrict__ Wu,
    const float* __restrict__ Sg, const float* __restrict__ Su,
    const float* __restrict__ Wd, const float* __restrict__ Sd,
    unsigned short* __restrict__ xb, unsigned short* __restrict__ Wgu, unsigned short* __restrict__ Sgu,
    unsigned short* __restrict__ WdT, unsigned short* __restrict__ SdT)
{
  __shared__ __attribute__((aligned(16))) unsigned short tl[64 * 64];
  int bid = blockIdx.x;
  if (bid < 2048) {
    size_t i = ((size_t)bid * 256 + threadIdx.x) * 8;
    f32x4 v0 = *(const f32x4*)(x + i), v1 = *(const f32x4*)(x + i + 4);
    u32x4 pk = { pk2(v0[0],v0[1]), pk2(v0[2],v0[3]), pk2(v1[0],v1[1]), pk2(v1[2],v1[3]) };
    *(u32x4*)&xb[i] = pk;
    return;
  }
  bid -= 2048;
  if (bid < 9216) {
    int z = bid >> 9, rem = bid & 511;
    int bx = rem & 31, by = rem >> 5;
    const float* src; unsigned short* dst; int mode;
    if (z < 8)        { src = Wg + (size_t)z * HD * ID;       dst = Wgu + (size_t)z * 4096 * 1024; mode = 1; }
    else if (z < 16)  { src = Wu + (size_t)(z - 8) * HD * ID; dst = Wgu + (size_t)(z - 8) * 4096 * 1024; mode = 2; }
    else if (z == 16) { src = Sg; dst = Sgu; mode = 1; }
    else              { src = Su; dst = Sgu; mode = 2; }
    tcvt_tile(src, dst, HD, ID, mode, by * 64, bx * 64, tl);
    return;
  }
  bid -= 9216;
  {
    int z = bid >> 9, rem = bid & 511;
    int bx = rem & 15, by = rem >> 4;
    const float* src = (z < 8) ? Wd + (size_t)z * ID * HD : Sd;
    unsigned short* dst = (z < 8) ? WdT + (size_t)z * ID * HD : SdT;
    tcvt_tile(src, dst, ID, HD, 0, by * 64, bx * 64, tl);
  }
}

// ================= GEMM1: 256x256 virtual (gate|up interleaved), fat 4-phase =================
__global__ __launch_bounds__(512, 2) void k_mlp1(
    const unsigned short* __restrict__ xb,
    const unsigned short* __restrict__ Wgu, const unsigned short* __restrict__ Sgu,
    const int* __restrict__ cnt, const int* __restrict__ base, const int* __restrict__ tokens,
    unsigned short* __restrict__ act)
{
  __shared__ __attribute__((aligned(16))) unsigned short Abuf[2][16384];
  __shared__ __attribute__((aligned(16))) unsigned short Bbuf[2][16384];

  // bijective XCD-chunked swizzle: 2304 = 8 x 288; n-panel-major within chunk
  const int g = (blockIdx.x & 7) * 288 + (blockIdx.x >> 3);
  const int e = g >> 8;
  const int r_ = g & 255;
  const int nx = r_ & 15, my = r_ >> 4;
  const int cntE = (e == NE) ? T_TOK : cnt[e];
  const int m0 = my * 256;
  if (m0 >= cntE) return;
  const int n0 = nx * 256;
  const unsigned short* Bsrc = (e == NE) ? Sgu : Wgu + (size_t)e * 4096 * 1024;
  const int rowbase = (e == NE) ? 2 * T_TOK : base[e];
  const int tid = threadIdx.x, lane = tid & 63, w = tid >> 6;
  const int srow = tid >> 3;
  const int kgf = (tid & 7) ^ (srow & 7);

  const unsigned short* asrc[4]; const unsigned short* bsrc[4];
  #pragma unroll
  for (int u = 0; u < 4; ++u) {
    int r = u * 64 + srow;
    int rl = min(m0 + r, cntE - 1);
    int tok = (e == NE) ? rl : tokens[e * T_TOK + rl];
    asrc[u] = xb + (size_t)tok * HD + kgf * 8;
    bsrc[u] = Bsrc + (size_t)(n0 + r) * HD + kgf * 8;
  }

  f32x4 acc[8][4];
  const f32x4 z4 = {0.f, 0.f, 0.f, 0.f};
  #pragma unroll
  for (int i = 0; i < 8; ++i)
    #pragma unroll
    for (int j = 0; j < 4; ++j) acc[i][j] = z4;

  const int lr = lane & 15, lg = lane >> 4;
  const int wm = (w >> 2) * 128;
  const int wn4 = (w & 3) * 64;
  const int ck0 = (lg ^ (lr & 7)) * 16;
  const int arow0 = (wm + lr) * 128;
  const int brow0 = (wn4 + lr) * 128;

  bf16x8 af[4][2], bf[2][2][2];

  #define SA1(t_, h_, s_) { \
    gl16(asrc[(h_)*2+0] + (t_)*64, &Abuf[s_][(h_)*8192 + 0    + w*512]); \
    gl16(asrc[(h_)*2+1] + (t_)*64, &Abuf[s_][(h_)*8192 + 4096 + w*512]); }
  #define SB1(t_, h_, s_) { \
    gl16(bsrc[(h_)*2+0] + (t_)*64, &Bbuf[s_][(h_)*8192 + 0    + w*512]); \
    gl16(bsrc[(h_)*2+1] + (t_)*64, &Bbuf[s_][(h_)*8192 + 4096 + w*512]); }
  #define LDA1(s_, mh_) { _Pragma("unroll") for (int am_ = 0; am_ < 4; ++am_) { \
    af[am_][0] = *(const bf16x8*)((const char*)&Abuf[s_][0] + arow0 + (mh_)*8192 + am_*2048 + ck0); \
    af[am_][1] = *(const bf16x8*)((const char*)&Abuf[s_][0] + arow0 + (mh_)*8192 + am_*2048 + (ck0^64)); } }
  #define LDB1(s_, nh_) { _Pragma("unroll") for (int bn_ = 0; bn_ < 2; ++bn_) { \
    bf[nh_][bn_][0] = *(const bf16x8*)((const char*)&Bbuf[s_][0] + brow0 + (nh_)*4096 + bn_*2048 + ck0); \
    bf[nh_][bn_][1] = *(const bf16x8*)((const char*)&Bbuf[s_][0] + brow0 + (nh_)*4096 + bn_*2048 + (ck0^64)); } }
  #define MM1(mh_, nh_) { __builtin_amdgcn_s_setprio(1); \
    _Pragma("unroll") for (int bn_ = 0; bn_ < 2; ++bn_) \
      _Pragma("unroll") for (int am_ = 0; am_ < 4; ++am_) { \
        acc[(mh_)*4+am_][(nh_)*2+bn_] = __builtin_amdgcn_mfma_f32_16x16x32_bf16(af[am_][0], bf[nh_][bn_][0], acc[(mh_)*4+am_][(nh_)*2+bn_], 0,0,0); \
        acc[(mh_)*4+am_][(nh_)*2+bn_] = __builtin_amdgcn_mfma_f32_16x16x32_bf16(af[am_][1], bf[nh_][bn_][1], acc[(mh_)*4+am_][(nh_)*2+bn_], 0,0,0); } \
    __builtin_amdgcn_s_setprio(0); }

  const int NT1 = 16;
  SA1(0, 0, 0); SA1(0, 1, 0); SB1(0, 0, 0); SB1(0, 1, 0);
  SB1(1, 0, 1); SB1(1, 1, 1);
  WAITV(4);
  BAR();

  #define TILE1(t_, s_, o_) { \
    LDA1(s_, 0); LDB1(s_, 0); LDB1(s_, 1); \
    if ((t_)+1 < NT1) { SA1((t_)+1, 0, o_); SA1((t_)+1, 1, o_); } \
    BAR(); LGKM0(); MM1(0, 0); MM1(0, 1); BAR(); \
    LDA1(s_, 1); \
    if ((t_)+2 < NT1) { SB1((t_)+2, 0, s_); SB1((t_)+2, 1, s_); } \
    BAR(); LGKM0(); MM1(1, 1); MM1(1, 0); \
    if ((t_)+2 < NT1) { WAITV(4); } else { WAITV(0); } \
    BAR(); }

  for (int t = 0; t < NT1; t += 2) {
    TILE1(t, 0, 1);
    TILE1(t + 1, 1, 0);
  }
  #undef TILE1

  const int colbase = ((n0 + wn4) >> 1);
  #pragma unroll
  for (int mf = 0; mf < 8; ++mf) {
    const int rloc = wm + (mf >> 2) * 64 + (mf & 3) * 16 + lg * 4;
    #pragma unroll
    for (int p = 0; p < 2; ++p) {
      f32x4 gv = acc[mf][p], uv = acc[mf][p + 2];
      int col = colbase + p * 16 + lr;
      #pragma unroll
      for (int q = 0; q < 4; ++q) {
        int r = rloc + q;
        if (m0 + r < cntE) {
          float g_ = gv[q], u_ = uv[q];
          act[(size_t)(rowbase + m0 + r) * ID + col] = f2bf((g_ / (1.f + __expf(-g_))) * u_);
        }
      }
    }
  }
}

// ================= GEMM2: 256x256, split-K=2, fat 4-phase =================
__global__ __launch_bounds__(512, 2) void k_mlp2(
    const unsigned short* __restrict__ act,
    const unsigned short* __restrict__ WdT, const unsigned short* __restrict__ SdT,
    const int* __restrict__ cnt, const int* __restrict__ base,
    unsigned short* __restrict__ dn0, unsigned short* __restrict__ dn1)
{
  __shared__ __attribute__((aligned(16))) unsigned short Abuf[2][16384];
  __shared__ __attribute__((aligned(16))) unsigned short Bbuf[2][16384];

  // bijective XCD swizzle: 1152 = 8 x 144; n-panel-major within chunk
  const int g = (blockIdx.x & 7) * 144 + (blockIdx.x >> 3);
  const int z = g >> 6;
  const int r_ = g & 63;
  const int nx = r_ & 3, my = r_ >> 2;
  const int e = z >> 1, kh = z & 1;
  const int cntE = (e == NE) ? T_TOK : cnt[e];
  const int m0 = my * 256;
  if (m0 >= cntE) return;
  const int n0 = nx * 256;
  const unsigned short* Bsrc = (e == NE) ? SdT : WdT + (size_t)e * ID * HD;
  const int rowbase = (e == NE) ? 2 * T_TOK : base[e];
  const int koff = kh * 1024;
  const int tid = threadIdx.x, lane = tid & 63, w = tid >> 6;
  const int srow = tid >> 3;
  const int kgf = (tid & 7) ^ (srow & 7);

  const unsigned short* asrc[4]; const unsigned short* bsrc[4];
  #pragma unroll
  for (int u = 0; u < 4; ++u) {
    int r = u * 64 + srow;
    int rl = rowbase + min(m0 + r, cntE - 1);
    asrc[u] = act + (size_t)rl * ID + koff + kgf * 8;
    bsrc[u] = Bsrc + (size_t)(n0 + r) * ID + koff + kgf * 8;
  }

  f32x4 acc[8][4];
  const f32x4 z4 = {0.f, 0.f, 0.f, 0.f};
  #pragma unroll
  for (int i = 0; i < 8; ++i)
    #pragma unroll
    for (int j = 0; j < 4; ++j) acc[i][j] = z4;

  const int lr = lane & 15, lg = lane >> 4;
  const int wm = (w >> 2) * 128;
  const int wn4 = (w & 3) * 64;
  const int ck0 = (lg ^ (lr & 7)) * 16;
  const int arow0 = (wm + lr) * 128;
  const int brow0 = (wn4 + lr) * 128;

  bf16x8 af[4][2], bf[2][2][2];

  #define SA2(t_, h_, s_) { \
    gl16(asrc[(h_)*2+0] + (t_)*64, &Abuf[s_][(h_)*8192 + 0    + w*512]); \
    gl16(asrc[(h_)*2+1] + (t_)*64, &Abuf[s_][(h_)*8192 + 4096 + w*512]); }
  #define SB2(t_, h_, s_) { \
    gl16(bsrc[(h_)*2+0] + (t_)*64, &Bbuf[s_][(h_)*8192 + 0    + w*512]); \
    gl16(bsrc[(h_)*2+1] + (t_)*64, &Bbuf[s_][(h_)*8192 + 4096 + w*512]); }
  #define LDA2(s_, mh_) { _Pragma("unroll") for (int am_ = 0; am_ < 4; ++am_) { \
    af[am_][0] = *(const bf16x8*)((const char*)&Abuf[s_][0] + arow0 + (mh_)*8192 + am_*2048 + ck0); \
    af[am_][1] = *(const bf16x8*)((const char*)&Abuf[s_][0] + arow0 + (mh_)*8192 + am_*2048 + (ck0^64)); } }
  #define LDB2(s_, nh_) { _Pragma("unroll") for (int bn_ = 0; bn_ < 2; ++bn_) { \
    bf[nh_][bn_][0] = *(const bf16x8*)((const char*)&Bbuf[s_][0] + brow0 + (nh_)*4096 + bn_*2048 + ck0); \
    bf[nh_][bn_][1] = *(const bf16x8*)((const char*)&Bbuf[s_][0] + brow0 + (nh_)*4096 + bn_*2048 + (ck0^64)); } }
  #define MM2(mh_, nh_) { __builtin_amdgcn_s_setprio(1); \
    _Pragma("unroll") for (int bn_ = 0; bn_ < 2; ++bn_) \
      _Pragma("unroll") for (int am_ = 0; am_ < 4; ++am_) { \
        acc[(mh_)*4+am_][(nh_)*2+bn_] = __builtin_amdgcn_mfma_f32_16x16x32_bf16(af[am_][0], bf[nh_][bn_][0], acc[(mh_)*4+am_][(nh_)*2+bn_], 0,0,0); \
        acc[(mh_)*4+am_][(nh_)*2+bn_] = __builtin_amdgcn_mfma_f32_16x16x32_bf16(af[am_][1], bf[nh_][bn_][1], acc[(mh_)*4+am_][(nh_)*2+bn_], 0,0,0); } \
    __builtin_amdgcn_s_setprio(0); }

  const int NT2 = 16;
  SA2(0, 0, 0); SA2(0, 1, 0); SB2(0, 0, 0); SB2(0, 1, 0);
  SB2(1, 0, 1); SB2(1, 1, 1);
  WAITV(4);
  BAR();

  #define TILE2(t_, s_, o_) { \
    LDA2(s_, 0); LDB2(s_, 0); LDB2(s_, 1); \
    if ((t_)+1 < NT2) { SA2((t_)+1, 0, o_); SA2((t_)+1, 1, o_); } \
    BAR(); LGKM0(); MM2(0, 0); MM2(0, 1); BAR(); \
    LDA2(s_, 1); \
    if ((t_)+2 < NT2) { SB2((t_)+2, 0, s_); SB2((t_)+2, 1, s_); } \
    BAR(); LGKM0(); MM2(1, 1); MM2(1, 0); \
    if ((t_)+2 < NT2) { WAITV(4); } else { WAITV(0); } \
    BAR(); }

  for (int t = 0; t < NT2; t += 2) {
    TILE2(t, 0, 1);
    TILE2(t + 1, 1, 0);
  }
  #undef TILE2
  #undef SA2
  #undef SB2
  #undef LDA2
  #undef LDB2
  #undef MM2

  unsigned short* dnp = kh ? dn1 : dn0;
  #pragma unroll
  for (int mf = 0; mf < 8; ++mf) {
    const int rloc = wm + (mf >> 2) * 64 + (mf & 3) * 16 + lg * 4;
    #pragma unroll
    for (int nf = 0; nf < 4; ++nf) {
      f32x4 av = acc[mf][nf];
      int col = n0 + wn4 + nf * 16 + lr;
      #pragma unroll
      for (int q = 0; q < 4; ++q) {
        int r = rloc + q;
        if (m0 + r < cntE)
          dnp[(size_t)(rowbase + m0 + r) * HD + col] = f2bf(av[q]);
      }
    }
  }
}

// ---------------- combine ----------------
__global__ __launch_bounds__(256) void k_comb(const unsigned short* __restrict__ dn0,
    const unsigned short* __restrict__ dn1,
    const int* __restrict__ base, const int* __restrict__ slotrec,
    const float* __restrict__ wts, float* __restrict__ out)
{
  const int t = blockIdx.x;
  const int c = threadIdx.x * 4;
  int r0 = slotrec[t * 2], r1 = slotrec[t * 2 + 1];
  int e0 = r0 >> 16, p0 = r0 & 0xffff;
  int e1 = r1 >> 16, p1 = r1 & 0xffff;
  size_t s0 = (size_t)(base[e0] + p0) * HD + c;
  size_t s1 = (size_t)(base[e1] + p1) * HD + c;
  size_t sh = (size_t)(2 * T_TOK + t) * HD + c;
  float w0 = wts[e0 * T_TOK + p0], w1 = wts[e1 * T_TOK + p1];
  u32x2 vs0 = *(const u32x2*)&dn0[sh], vs1 = *(const u32x2*)&dn1[sh];
  u32x2 va0 = *(const u32x2*)&dn0[s0], va1 = *(const u32x2*)&dn1[s0];
  u32x2 vb0 = *(const u32x2*)&dn0[s1], vb1 = *(const u32x2*)&dn1[s1];
  f32x4 o;
  o[0] = (bflo(vs0[0]) + bflo(vs1[0])) + w0 * (bflo(va0[0]) + bflo(va1[0])) + w1 * (bflo(vb0[0]) + bflo(vb1[0]));
  o[1] = (bfhi(vs0[0]) + bfhi(vs1[0])) + w0 * (bfhi(va0[0]) + bfhi(va1[0])) + w1 * (bfhi(vb0[0]) + bfhi(vb1[0]));
  o[2] = (bflo(vs0[1]) + bflo(vs1[1])) + w0 * (bflo(va0[1]) + bflo(va1[1])) + w1 * (bflo(vb0[1]) + bflo(vb1[1]));
  o[3] = (bfhi(vs0[1]) + bfhi(vs1[1])) + w0 * (bfhi(va0[1]) + bfhi(va1[1])) + w1 * (bfhi(vb0[1]) + bfhi(vb1[1]));
  *(f32x4*)&out[(size_t)t * HD + c] = o;
}

extern "C" void kernel_launch(void* const* d_in, const int* in_sizes, int n_in,
                              void* d_out, int out_size, void* d_ws, size_t ws_size,
                              hipStream_t stream)
{
  const float* x    = (const float*)d_in[0];
  const float* gw   = (const float*)d_in[1];
  const float* bias = (const float*)d_in[2];
  const float* Wg   = (const float*)d_in[3];
  const float* Wu   = (const float*)d_in[4];
  const float* Wd   = (const float*)d_in[5];
  const float* Sg   = (const float*)d_in[6];
  const float* Su   = (const float*)d_in[7];
  const float* Sd   = (const float*)d_in[8];
  float* out = (float*)d_out;
  char* ws = (char*)d_ws;

  int*   cnt     = (int*)ws;
  int*   base    = cnt + 16;
  int*   tokens  = (int*)(ws + 512);
  float* wts     = (float*)(ws + 512 + (NE * T_TOK * 4));
  int*   slotrec = (int*)(ws + 512 + 2 * (NE * T_TOK * 4));

  const size_t MB = (size_t)1 << 20;
  unsigned short* xbf = (unsigned short*)(ws + 1 * MB);    // 8 MB
  unsigned short* WdT = (unsigned short*)(ws + 9 * MB);    // 32 MB
  unsigned short* SdT = (unsigned short*)(ws + 41 * MB);   // 4 MB
  unsigned short* Wgu = (unsigned short*)(ws + 45 * MB);   // 64 MB (dead after mlp1)
  unsigned short* Sgu = (unsigned short*)(ws + 109 * MB);  // 8 MB (dead after mlp1)
  unsigned short* actb = (unsigned short*)(ws + 117 * MB); // 48 MB
  unsigned short* dn0 = (unsigned short*)(ws + 45 * MB);   // 24 MB, overlays Wgu
  unsigned short* dn1 = (unsigned short*)(ws + 69 * MB);   // 24 MB, overlays Wgu

  k_zero<<<dim3(1), dim3(64), 0, stream>>>(cnt);
  k_route<<<dim3(T_TOK / 4), dim3(256), 0, stream>>>(x, gw, bias, cnt, tokens, wts, slotrec);
  k_fin<<<dim3(1), dim3(64), 0, stream>>>(cnt, base, out);
  k_conv<<<dim3(2048 + 9216 + 4608), dim3(256), 0, stream>>>(x, Wg, Wu, Sg, Su, Wd, Sd,
                                                             xbf, Wgu, Sgu, WdT, SdT);
  k_mlp1<<<dim3(2304), dim3(512), 0, stream>>>(xbf, Wgu, Sgu, cnt, base, tokens, actb);
  k_mlp2<<<dim3(1152), dim3(512), 0, stream>>>(actb, WdT, SdT, cnt, base, dn0, dn1);
  k_comb<<<dim3(T_TOK), dim3(256), 0, stream>>>(dn0, dn1, base, slotrec, wts, out);
}

// Round 10
// 401.466 us; speedup vs baseline: 9.3620x; 1.3857x over previous
//
#include <hip/hip_runtime.h>
#include <hip/hip_bf16.h>

#define T_TOK 4096
#define HD 1024
#define ID 2048
#define NE 8

typedef __attribute__((ext_vector_type(8))) __bf16 bf16x8;
typedef __attribute__((ext_vector_type(4))) float f32x4;
typedef __attribute__((ext_vector_type(4))) unsigned int u32x4;
typedef __attribute__((ext_vector_type(2))) unsigned int u32x2;

#define AS1 __attribute__((address_space(1)))
#define AS3 __attribute__((address_space(3)))

#define WAITV(N) asm volatile("s_waitcnt vmcnt(" #N ")" ::: "memory")
#define BAR()    asm volatile("s_barrier" ::: "memory")
#define LGKM0()  { asm volatile("s_waitcnt lgkmcnt(0)" ::: "memory"); __builtin_amdgcn_sched_barrier(0); }

__device__ __forceinline__ unsigned short f2bf(float f) {
  __hip_bfloat16 h = __float2bfloat16(f);
  return __builtin_bit_cast(unsigned short, h);
}
__device__ __forceinline__ unsigned int pk2(float lo, float hi) {
  return (unsigned int)f2bf(lo) | ((unsigned int)f2bf(hi) << 16);
}
__device__ __forceinline__ float bflo(unsigned int u) { return __builtin_bit_cast(float, u << 16); }
__device__ __forceinline__ float bfhi(unsigned int u) { return __builtin_bit_cast(float, u & 0xffff0000u); }
__device__ __forceinline__ void gl16(const void* g, void* l) {
  __builtin_amdgcn_global_load_lds((const AS1 unsigned int*)g, (AS3 unsigned int*)l, 16, 0, 0);
}

// ---------------- routing ----------------
__global__ void k_zero(int* cnt) { if (threadIdx.x < 32) cnt[threadIdx.x] = 0; }

__global__ __launch_bounds__(256) void k_route(const float* __restrict__ x,
    const float* __restrict__ gw, const float* __restrict__ bias,
    int* __restrict__ cnt, int* __restrict__ tokens, float* __restrict__ wts,
    int* __restrict__ slotrec)
{
  const int lane = threadIdx.x & 63;
  const int t = blockIdx.x * 4 + (threadIdx.x >> 6);
  const float* xr = x + (size_t)t * HD + lane * 16;
  f32x4 xv[4];
  #pragma unroll
  for (int j = 0; j < 4; ++j) xv[j] = *(const f32x4*)(xr + j * 4);
  float sc[NE];
  #pragma unroll
  for (int e = 0; e < NE; ++e) {
    const float* gr = gw + e * HD + lane * 16;
    float a = 0.f;
    #pragma unroll
    for (int j = 0; j < 4; ++j) {
      f32x4 gv = *(const f32x4*)(gr + j * 4);
      a += xv[j][0]*gv[0] + xv[j][1]*gv[1] + xv[j][2]*gv[2] + xv[j][3]*gv[3];
    }
    #pragma unroll
    for (int off = 32; off > 0; off >>= 1) a += __shfl_xor(a, off);
    sc[e] = a;
  }
  int i1 = 0; float b1 = sc[0] + bias[0];
  #pragma unroll
  for (int e = 1; e < NE; ++e) { float be = sc[e] + bias[e]; if (be > b1) { b1 = be; i1 = e; } }
  int i2 = -1; float b2 = -3e38f;
  #pragma unroll
  for (int e = 0; e < NE; ++e) { if (e == i1) continue; float be = sc[e] + bias[e]; if (be > b2) { b2 = be; i2 = e; } }
  int a1 = 0; float r1 = sc[0];
  #pragma unroll
  for (int e = 1; e < NE; ++e) if (sc[e] > r1) { r1 = sc[e]; a1 = e; }
  float r2 = -3e38f;
  #pragma unroll
  for (int e = 0; e < NE; ++e) if (e != a1 && sc[e] > r2) r2 = sc[e];
  float w1 = 1.f / (1.f + __expf(-r1));
  float w2 = 1.f / (1.f + __expf(-r2));
  float s = w1 + w2; w1 /= s; w2 /= s;
  if (lane == 0) {
    int p = atomicAdd(&cnt[i1], 1); tokens[i1 * T_TOK + p] = t; wts[i1 * T_TOK + p] = w1;
    slotrec[t * 2] = (i1 << 16) | p;
    p = atomicAdd(&cnt[i2], 1);     tokens[i2 * T_TOK + p] = t; wts[i2 * T_TOK + p] = w2;
    slotrec[t * 2 + 1] = (i2 << 16) | p;
  }
}

__global__ void k_fin(const int* __restrict__ cnt, int* __restrict__ base, float* __restrict__ out)
{
  if (threadIdx.x == 0) {
    int b = 0, mx = 0;
    #pragma unroll
    for (int e = 0; e < NE; ++e) { base[e] = b; b += cnt[e]; if (cnt[e] > mx) mx = cnt[e]; }
    base[NE] = b;
    out[(size_t)T_TOK * HD] = (float)mx * (1.f / 1024.f) - 1.f;  // viol
  }
}

// ---------------- fused converts ----------------
__device__ __forceinline__ void tcvt_tile(const float* __restrict__ src, unsigned short* __restrict__ dst,
                                          int K, int N, int mode, int k0, int n0, unsigned short* tl)
{
  const int t = threadIdx.x;
  const int nc = (t & 15) * 4;
  #pragma unroll
  for (int it = 0; it < 4; ++it) {
    int kr = (t >> 4) + it * 16;
    f32x4 v = *(const f32x4*)&src[(size_t)(k0 + kr) * N + n0 + nc];
    #pragma unroll
    for (int j = 0; j < 4; ++j) {
      int n = nc + j;
      tl[n * 64 + (((kr >> 3) ^ (n & 7)) * 8) + (kr & 7)] = f2bf(v[j]);
    }
  }
  __syncthreads();
  #pragma unroll
  for (int it = 0; it < 2; ++it) {
    int idx = t + it * 256;
    int n = idx >> 3, kc8 = idx & 7;
    u32x4 v = *(const u32x4*)&tl[n * 64 + ((kc8 ^ (n & 7)) * 8)];
    int nn = n0 + n;
    int vrow = (mode == 0) ? nn : (((nn >> 5) << 6) + (nn & 31) + ((mode == 2) ? 32 : 0));
    *(u32x4*)&dst[(size_t)vrow * K + k0 + kc8 * 8] = v;
  }
}

// blocks 0..2047: x fp32->bf16; 2048..11263: Wg/Wu/Sg/Su -> Wgu/Sgu; 11264..15871: Wd/Sd -> WdT/SdT
__global__ __launch_bounds__(256) void k_conv(const float* __restrict__ x,
    const float* __restrict__ Wg, const float* __restrict__ Wu,
    const float* __restrict__ Sg, const float* __restrict__ Su,
    const float* __restrict__ Wd, const float* __restrict__ Sd,
    unsigned short* __restrict__ xb, unsigned short* __restrict__ Wgu, unsigned short* __restrict__ Sgu,
    unsigned short* __restrict__ WdT, unsigned short* __restrict__ SdT)
{
  __shared__ __attribute__((aligned(16))) unsigned short tl[64 * 64];
  int bid = blockIdx.x;
  if (bid < 2048) {
    size_t i = ((size_t)bid * 256 + threadIdx.x) * 8;
    f32x4 v0 = *(const f32x4*)(x + i), v1 = *(const f32x4*)(x + i + 4);
    u32x4 pk = { pk2(v0[0],v0[1]), pk2(v0[2],v0[3]), pk2(v1[0],v1[1]), pk2(v1[2],v1[3]) };
    *(u32x4*)&xb[i] = pk;
    return;
  }
  bid -= 2048;
  if (bid < 9216) {
    int z = bid >> 9, rem = bid & 511;
    int bx = rem & 31, by = rem >> 5;
    const float* src; unsigned short* dst; int mode;
    if (z < 8)        { src = Wg + (size_t)z * HD * ID;       dst = Wgu + (size_t)z * 4096 * 1024; mode = 1; }
    else if (z < 16)  { src = Wu + (size_t)(z - 8) * HD * ID; dst = Wgu + (size_t)(z - 8) * 4096 * 1024; mode = 2; }
    else if (z == 16) { src = Sg; dst = Sgu; mode = 1; }
    else              { src = Su; dst = Sgu; mode = 2; }
    tcvt_tile(src, dst, HD, ID, mode, by * 64, bx * 64, tl);
    return;
  }
  bid -= 9216;
  {
    int z = bid >> 9, rem = bid & 511;
    int bx = rem & 15, by = rem >> 4;
    const float* src = (z < 8) ? Wd + (size_t)z * ID * HD : Sd;
    unsigned short* dst = (z < 8) ? WdT + (size_t)z * ID * HD : SdT;
    tcvt_tile(src, dst, ID, HD, 0, by * 64, bx * 64, tl);
  }
}

// ================= GEMM1: 256x256 virtual (gate|up interleaved), fat 4-phase =================
__global__ __launch_bounds__(512, 2) void k_mlp1(
    const unsigned short* __restrict__ xb,
    const unsigned short* __restrict__ Wgu, const unsigned short* __restrict__ Sgu,
    const int* __restrict__ cnt, const int* __restrict__ base, const int* __restrict__ tokens,
    unsigned short* __restrict__ act)
{
  __shared__ __attribute__((aligned(16))) unsigned short Abuf[2][16384];
  __shared__ __attribute__((aligned(16))) unsigned short Bbuf[2][16384];

  const int e = blockIdx.z;
  const int cntE = (e == NE) ? T_TOK : cnt[e];
  const int m0 = blockIdx.y * 256;
  if (m0 >= cntE) return;
  const int n0 = blockIdx.x * 256;
  const unsigned short* Bsrc = (e == NE) ? Sgu : Wgu + (size_t)e * 4096 * 1024;
  const int rowbase = (e == NE) ? 2 * T_TOK : base[e];
  const int tid = threadIdx.x, lane = tid & 63, w = tid >> 6;
  const int srow = tid >> 3;
  const int kgf = (tid & 7) ^ (srow & 7);

  const unsigned short* asrc[4]; const unsigned short* bsrc[4];
  #pragma unroll
  for (int u = 0; u < 4; ++u) {
    int r = u * 64 + srow;
    int rl = min(m0 + r, cntE - 1);
    int tok = (e == NE) ? rl : tokens[e * T_TOK + rl];
    asrc[u] = xb + (size_t)tok * HD + kgf * 8;
    bsrc[u] = Bsrc + (size_t)(n0 + r) * HD + kgf * 8;
  }

  f32x4 acc[8][4];
  const f32x4 z4 = {0.f, 0.f, 0.f, 0.f};
  #pragma unroll
  for (int i = 0; i < 8; ++i)
    #pragma unroll
    for (int j = 0; j < 4; ++j) acc[i][j] = z4;

  const int lr = lane & 15, lg = lane >> 4;
  const int wm = (w >> 2) * 128;
  const int wn4 = (w & 3) * 64;
  const int ck0 = (lg ^ (lr & 7)) * 16;
  const int arow0 = (wm + lr) * 128;
  const int brow0 = (wn4 + lr) * 128;

  bf16x8 af[4][2], bf[2][2][2];

  #define SA1(t_, h_, s_) { \
    gl16(asrc[(h_)*2+0] + (t_)*64, &Abuf[s_][(h_)*8192 + 0    + w*512]); \
    gl16(asrc[(h_)*2+1] + (t_)*64, &Abuf[s_][(h_)*8192 + 4096 + w*512]); }
  #define SB1(t_, h_, s_) { \
    gl16(bsrc[(h_)*2+0] + (t_)*64, &Bbuf[s_][(h_)*8192 + 0    + w*512]); \
    gl16(bsrc[(h_)*2+1] + (t_)*64, &Bbuf[s_][(h_)*8192 + 4096 + w*512]); }
  #define LDA1(s_, mh_) { _Pragma("unroll") for (int am_ = 0; am_ < 4; ++am_) { \
    af[am_][0] = *(const bf16x8*)((const char*)&Abuf[s_][0] + arow0 + (mh_)*8192 + am_*2048 + ck0); \
    af[am_][1] = *(const bf16x8*)((const char*)&Abuf[s_][0] + arow0 + (mh_)*8192 + am_*2048 + (ck0^64)); } }
  #define LDB1(s_, nh_) { _Pragma("unroll") for (int bn_ = 0; bn_ < 2; ++bn_) { \
    bf[nh_][bn_][0] = *(const bf16x8*)((const char*)&Bbuf[s_][0] + brow0 + (nh_)*4096 + bn_*2048 + ck0); \
    bf[nh_][bn_][1] = *(const bf16x8*)((const char*)&Bbuf[s_][0] + brow0 + (nh_)*4096 + bn_*2048 + (ck0^64)); } }
  #define MM1(mh_, nh_) { __builtin_amdgcn_s_setprio(1); \
    _Pragma("unroll") for (int bn_ = 0; bn_ < 2; ++bn_) \
      _Pragma("unroll") for (int am_ = 0; am_ < 4; ++am_) { \
        acc[(mh_)*4+am_][(nh_)*2+bn_] = __builtin_amdgcn_mfma_f32_16x16x32_bf16(af[am_][0], bf[nh_][bn_][0], acc[(mh_)*4+am_][(nh_)*2+bn_], 0,0,0); \
        acc[(mh_)*4+am_][(nh_)*2+bn_] = __builtin_amdgcn_mfma_f32_16x16x32_bf16(af[am_][1], bf[nh_][bn_][1], acc[(mh_)*4+am_][(nh_)*2+bn_], 0,0,0); } \
    __builtin_amdgcn_s_setprio(0); }

  const int NT1 = 16;
  SA1(0, 0, 0); SA1(0, 1, 0); SB1(0, 0, 0); SB1(0, 1, 0);
  SB1(1, 0, 1); SB1(1, 1, 1);
  WAITV(4);
  BAR();

  #define TILE1(t_, s_, o_) { \
    LDA1(s_, 0); LDB1(s_, 0); LDB1(s_, 1); \
    if ((t_)+1 < NT1) { SA1((t_)+1, 0, o_); SA1((t_)+1, 1, o_); } \
    BAR(); LGKM0(); MM1(0, 0); MM1(0, 1); BAR(); \
    LDA1(s_, 1); \
    if ((t_)+2 < NT1) { SB1((t_)+2, 0, s_); SB1((t_)+2, 1, s_); } \
    BAR(); LGKM0(); MM1(1, 1); MM1(1, 0); \
    if ((t_)+2 < NT1) { WAITV(4); } else { WAITV(0); } \
    BAR(); }

  for (int t = 0; t < NT1; t += 2) {
    TILE1(t, 0, 1);
    TILE1(t + 1, 1, 0);
  }
  #undef TILE1

  const int colbase = ((n0 + wn4) >> 1);
  #pragma unroll
  for (int mf = 0; mf < 8; ++mf) {
    const int rloc = wm + (mf >> 2) * 64 + (mf & 3) * 16 + lg * 4;
    #pragma unroll
    for (int p = 0; p < 2; ++p) {
      f32x4 gv = acc[mf][p], uv = acc[mf][p + 2];
      int col = colbase + p * 16 + lr;
      #pragma unroll
      for (int q = 0; q < 4; ++q) {
        int r = rloc + q;
        if (m0 + r < cntE) {
          float g_ = gv[q], u_ = uv[q];
          act[(size_t)(rowbase + m0 + r) * ID + col] = f2bf((g_ / (1.f + __expf(-g_))) * u_);
        }
      }
    }
  }
}

// ================= GEMM2: 256x256, split-K=2, fat 4-phase =================
__global__ __launch_bounds__(512, 2) void k_mlp2(
    const unsigned short* __restrict__ act,
    const unsigned short* __restrict__ WdT, const unsigned short* __restrict__ SdT,
    const int* __restrict__ cnt, const int* __restrict__ base,
    unsigned short* __restrict__ dn0, unsigned short* __restrict__ dn1)
{
  __shared__ __attribute__((aligned(16))) unsigned short Abuf[2][16384];
  __shared__ __attribute__((aligned(16))) unsigned short Bbuf[2][16384];

  const int e = blockIdx.z >> 1;
  const int kh = blockIdx.z & 1;
  const int cntE = (e == NE) ? T_TOK : cnt[e];
  const int m0 = blockIdx.y * 256;
  if (m0 >= cntE) return;
  const int n0 = blockIdx.x * 256;
  const unsigned short* Bsrc = (e == NE) ? SdT : WdT + (size_t)e * ID * HD;
  const int rowbase = (e == NE) ? 2 * T_TOK : base[e];
  const int koff = kh * 1024;
  const int tid = threadIdx.x, lane = tid & 63, w = tid >> 6;
  const int srow = tid >> 3;
  const int kgf = (tid & 7) ^ (srow & 7);

  const unsigned short* asrc[4]; const unsigned short* bsrc[4];
  #pragma unroll
  for (int u = 0; u < 4; ++u) {
    int r = u * 64 + srow;
    int rl = rowbase + min(m0 + r, cntE - 1);
    asrc[u] = act + (size_t)rl * ID + koff + kgf * 8;
    bsrc[u] = Bsrc + (size_t)(n0 + r) * ID + koff + kgf * 8;
  }

  f32x4 acc[8][4];
  const f32x4 z4 = {0.f, 0.f, 0.f, 0.f};
  #pragma unroll
  for (int i = 0; i < 8; ++i)
    #pragma unroll
    for (int j = 0; j < 4; ++j) acc[i][j] = z4;

  const int lr = lane & 15, lg = lane >> 4;
  const int wm = (w >> 2) * 128;
  const int wn4 = (w & 3) * 64;
  const int ck0 = (lg ^ (lr & 7)) * 16;
  const int arow0 = (wm + lr) * 128;
  const int brow0 = (wn4 + lr) * 128;

  bf16x8 af[4][2], bf[2][2][2];

  #define SA2(t_, h_, s_) { \
    gl16(asrc[(h_)*2+0] + (t_)*64, &Abuf[s_][(h_)*8192 + 0    + w*512]); \
    gl16(asrc[(h_)*2+1] + (t_)*64, &Abuf[s_][(h_)*8192 + 4096 + w*512]); }
  #define SB2(t_, h_, s_) { \
    gl16(bsrc[(h_)*2+0] + (t_)*64, &Bbuf[s_][(h_)*8192 + 0    + w*512]); \
    gl16(bsrc[(h_)*2+1] + (t_)*64, &Bbuf[s_][(h_)*8192 + 4096 + w*512]); }
  #define LDA2(s_, mh_) { _Pragma("unroll") for (int am_ = 0; am_ < 4; ++am_) { \
    af[am_][0] = *(const bf16x8*)((const char*)&Abuf[s_][0] + arow0 + (mh_)*8192 + am_*2048 + ck0); \
    af[am_][1] = *(const bf16x8*)((const char*)&Abuf[s_][0] + arow0 + (mh_)*8192 + am_*2048 + (ck0^64)); } }
  #define LDB2(s_, nh_) { _Pragma("unroll") for (int bn_ = 0; bn_ < 2; ++bn_) { \
    bf[nh_][bn_][0] = *(const bf16x8*)((const char*)&Bbuf[s_][0] + brow0 + (nh_)*4096 + bn_*2048 + ck0); \
    bf[nh_][bn_][1] = *(const bf16x8*)((const char*)&Bbuf[s_][0] + brow0 + (nh_)*4096 + bn_*2048 + (ck0^64)); } }
  #define MM2(mh_, nh_) { __builtin_amdgcn_s_setprio(1); \
    _Pragma("unroll") for (int bn_ = 0; bn_ < 2; ++bn_) \
      _Pragma("unroll") for (int am_ = 0; am_ < 4; ++am_) { \
        acc[(mh_)*4+am_][(nh_)*2+bn_] = __builtin_amdgcn_mfma_f32_16x16x32_bf16(af[am_][0], bf[nh_][bn_][0], acc[(mh_)*4+am_][(nh_)*2+bn_], 0,0,0); \
        acc[(mh_)*4+am_][(nh_)*2+bn_] = __builtin_amdgcn_mfma_f32_16x16x32_bf16(af[am_][1], bf[nh_][bn_][1], acc[(mh_)*4+am_][(nh_)*2+bn_], 0,0,0); } \
    __builtin_amdgcn_s_setprio(0); }

  const int NT2 = 16;
  SA2(0, 0, 0); SA2(0, 1, 0); SB2(0, 0, 0); SB2(0, 1, 0);
  SB2(1, 0, 1); SB2(1, 1, 1);
  WAITV(4);
  BAR();

  #define TILE2(t_, s_, o_) { \
    LDA2(s_, 0); LDB2(s_, 0); LDB2(s_, 1); \
    if ((t_)+1 < NT2) { SA2((t_)+1, 0, o_); SA2((t_)+1, 1, o_); } \
    BAR(); LGKM0(); MM2(0, 0); MM2(0, 1); BAR(); \
    LDA2(s_, 1); \
    if ((t_)+2 < NT2) { SB2((t_)+2, 0, s_); SB2((t_)+2, 1, s_); } \
    BAR(); LGKM0(); MM2(1, 1); MM2(1, 0); \
    if ((t_)+2 < NT2) { WAITV(4); } else { WAITV(0); } \
    BAR(); }

  for (int t = 0; t < NT2; t += 2) {
    TILE2(t, 0, 1);
    TILE2(t + 1, 1, 0);
  }
  #undef TILE2
  #undef SA2
  #undef SB2
  #undef LDA2
  #undef LDB2
  #undef MM2

  unsigned short* dnp = kh ? dn1 : dn0;
  #pragma unroll
  for (int mf = 0; mf < 8; ++mf) {
    const int rloc = wm + (mf >> 2) * 64 + (mf & 3) * 16 + lg * 4;
    #pragma unroll
    for (int nf = 0; nf < 4; ++nf) {
      f32x4 av = acc[mf][nf];
      int col = n0 + wn4 + nf * 16 + lr;
      #pragma unroll
      for (int q = 0; q < 4; ++q) {
        int r = rloc + q;
        if (m0 + r < cntE)
          dnp[(size_t)(rowbase + m0 + r) * HD + col] = f2bf(av[q]);
      }
    }
  }
}

// ---------------- combine ----------------
__global__ __launch_bounds__(256) void k_comb(const unsigned short* __restrict__ dn0,
    const unsigned short* __restrict__ dn1,
    const int* __restrict__ base, const int* __restrict__ slotrec,
    const float* __restrict__ wts, float* __restrict__ out)
{
  const int t = blockIdx.x;
  const int c = threadIdx.x * 4;
  int r0 = slotrec[t * 2], r1 = slotrec[t * 2 + 1];
  int e0 = r0 >> 16, p0 = r0 & 0xffff;
  int e1 = r1 >> 16, p1 = r1 & 0xffff;
  size_t s0 = (size_t)(base[e0] + p0) * HD + c;
  size_t s1 = (size_t)(base[e1] + p1) * HD + c;
  size_t sh = (size_t)(2 * T_TOK + t) * HD + c;
  float w0 = wts[e0 * T_TOK + p0], w1 = wts[e1 * T_TOK + p1];
  u32x2 vs0 = *(const u32x2*)&dn0[sh], vs1 = *(const u32x2*)&dn1[sh];
  u32x2 va0 = *(const u32x2*)&dn0[s0], va1 = *(const u32x2*)&dn1[s0];
  u32x2 vb0 = *(const u32x2*)&dn0[s1], vb1 = *(const u32x2*)&dn1[s1];
  f32x4 o;
  o[0] = (bflo(vs0[0]) + bflo(vs1[0])) + w0 * (bflo(va0[0]) + bflo(va1[0])) + w1 * (bflo(vb0[0]) + bflo(vb1[0]));
  o[1] = (bfhi(vs0[0]) + bfhi(vs1[0])) + w0 * (bfhi(va0[0]) + bfhi(va1[0])) + w1 * (bfhi(vb0[0]) + bfhi(vb1[0]));
  o[2] = (bflo(vs0[1]) + bflo(vs1[1])) + w0 * (bflo(va0[1]) + bflo(va1[1])) + w1 * (bflo(vb0[1]) + bflo(vb1[1]));
  o[3] = (bfhi(vs0[1]) + bfhi(vs1[1])) + w0 * (bfhi(va0[1]) + bfhi(va1[1])) + w1 * (bfhi(vb0[1]) + bfhi(vb1[1]));
  *(f32x4*)&out[(size_t)t * HD + c] = o;
}

extern "C" void kernel_launch(void* const* d_in, const int* in_sizes, int n_in,
                              void* d_out, int out_size, void* d_ws, size_t ws_size,
                              hipStream_t stream)
{
  const float* x    = (const float*)d_in[0];
  const float* gw   = (const float*)d_in[1];
  const float* bias = (const float*)d_in[2];
  const float* Wg   = (const float*)d_in[3];
  const float* Wu   = (const float*)d_in[4];
  const float* Wd   = (const float*)d_in[5];
  const float* Sg   = (const float*)d_in[6];
  const float* Su   = (const float*)d_in[7];
  const float* Sd   = (const float*)d_in[8];
  float* out = (float*)d_out;
  char* ws = (char*)d_ws;

  int*   cnt     = (int*)ws;
  int*   base    = cnt + 16;
  int*   tokens  = (int*)(ws + 512);
  float* wts     = (float*)(ws + 512 + (NE * T_TOK * 4));
  int*   slotrec = (int*)(ws + 512 + 2 * (NE * T_TOK * 4));

  const size_t MB = (size_t)1 << 20;
  unsigned short* xbf = (unsigned short*)(ws + 1 * MB);    // 8 MB
  unsigned short* WdT = (unsigned short*)(ws + 9 * MB);    // 32 MB
  unsigned short* SdT = (unsigned short*)(ws + 41 * MB);   // 4 MB
  unsigned short* Wgu = (unsigned short*)(ws + 45 * MB);   // 64 MB (dead after mlp1)
  unsigned short* Sgu = (unsigned short*)(ws + 109 * MB);  // 8 MB (dead after mlp1)
  unsigned short* actb = (unsigned short*)(ws + 117 * MB); // 48 MB
  unsigned short* dn0 = (unsigned short*)(ws + 45 * MB);   // 24 MB, overlays Wgu
  unsigned short* dn1 = (unsigned short*)(ws + 69 * MB);   // 24 MB, overlays Wgu

  k_zero<<<dim3(1), dim3(64), 0, stream>>>(cnt);
  k_route<<<dim3(T_TOK / 4), dim3(256), 0, stream>>>(x, gw, bias, cnt, tokens, wts, slotrec);
  k_fin<<<dim3(1), dim3(64), 0, stream>>>(cnt, base, out);
  k_conv<<<dim3(2048 + 9216 + 4608), dim3(256), 0, stream>>>(x, Wg, Wu, Sg, Su, Wd, Sd,
                                                             xbf, Wgu, Sgu, WdT, SdT);
  k_mlp1<<<dim3(16, 16, NE + 1), dim3(512), 0, stream>>>(xbf, Wgu, Sgu, cnt, base, tokens, actb);
  k_mlp2<<<dim3(4, 16, 2 * (NE + 1)), dim3(512), 0, stream>>>(actb, WdT, SdT, cnt, base, dn0, dn1);
  k_comb<<<dim3(T_TOK), dim3(256), 0, stream>>>(dn0, dn1, base, slotrec, wts, out);
}

// Round 11
// 381.301 us; speedup vs baseline: 9.8571x; 1.0529x over previous
//
#include <hip/hip_runtime.h>
#include <hip/hip_bf16.h>

#define T_TOK 4096
#define HD 1024
#define ID 2048
#define NE 8

typedef __attribute__((ext_vector_type(8))) __bf16 bf16x8;
typedef __attribute__((ext_vector_type(4))) float f32x4;
typedef __attribute__((ext_vector_type(4))) unsigned int u32x4;
typedef __attribute__((ext_vector_type(2))) unsigned int u32x2;

#define AS1 __attribute__((address_space(1)))
#define AS3 __attribute__((address_space(3)))

#define WAITV(N) asm volatile("s_waitcnt vmcnt(" #N ")" ::: "memory")
#define BAR()    asm volatile("s_barrier" ::: "memory")
#define LGKM0()  { asm volatile("s_waitcnt lgkmcnt(0)" ::: "memory"); __builtin_amdgcn_sched_barrier(0); }

__device__ __forceinline__ unsigned short f2bf(float f) {
  __hip_bfloat16 h = __float2bfloat16(f);
  return __builtin_bit_cast(unsigned short, h);
}
__device__ __forceinline__ unsigned int pk2(float lo, float hi) {
  return (unsigned int)f2bf(lo) | ((unsigned int)f2bf(hi) << 16);
}
__device__ __forceinline__ float bflo(unsigned int u) { return __builtin_bit_cast(float, u << 16); }
__device__ __forceinline__ float bfhi(unsigned int u) { return __builtin_bit_cast(float, u & 0xffff0000u); }
__device__ __forceinline__ void gl16(const void* g, void* l) {
  __builtin_amdgcn_global_load_lds((const AS1 unsigned int*)g, (AS3 unsigned int*)l, 16, 0, 0);
}

// ---------------- routing ----------------
__global__ void k_zero(int* cnt) { if (threadIdx.x < 32) cnt[threadIdx.x] = 0; }

__global__ __launch_bounds__(256) void k_route(const float* __restrict__ x,
    const float* __restrict__ gw, const float* __restrict__ bias,
    int* __restrict__ cnt, int* __restrict__ tokens, float* __restrict__ wts,
    int* __restrict__ slotrec)
{
  const int lane = threadIdx.x & 63;
  const int t = blockIdx.x * 4 + (threadIdx.x >> 6);
  const float* xr = x + (size_t)t * HD + lane * 16;
  f32x4 xv[4];
  #pragma unroll
  for (int j = 0; j < 4; ++j) xv[j] = *(const f32x4*)(xr + j * 4);
  float sc[NE];
  #pragma unroll
  for (int e = 0; e < NE; ++e) {
    const float* gr = gw + e * HD + lane * 16;
    float a = 0.f;
    #pragma unroll
    for (int j = 0; j < 4; ++j) {
      f32x4 gv = *(const f32x4*)(gr + j * 4);
      a += xv[j][0]*gv[0] + xv[j][1]*gv[1] + xv[j][2]*gv[2] + xv[j][3]*gv[3];
    }
    #pragma unroll
    for (int off = 32; off > 0; off >>= 1) a += __shfl_xor(a, off);
    sc[e] = a;
  }
  int i1 = 0; float b1 = sc[0] + bias[0];
  #pragma unroll
  for (int e = 1; e < NE; ++e) { float be = sc[e] + bias[e]; if (be > b1) { b1 = be; i1 = e; } }
  int i2 = -1; float b2 = -3e38f;
  #pragma unroll
  for (int e = 0; e < NE; ++e) { if (e == i1) continue; float be = sc[e] + bias[e]; if (be > b2) { b2 = be; i2 = e; } }
  int a1 = 0; float r1 = sc[0];
  #pragma unroll
  for (int e = 1; e < NE; ++e) if (sc[e] > r1) { r1 = sc[e]; a1 = e; }
  float r2 = -3e38f;
  #pragma unroll
  for (int e = 0; e < NE; ++e) if (e != a1 && sc[e] > r2) r2 = sc[e];
  float w1 = 1.f / (1.f + __expf(-r1));
  float w2 = 1.f / (1.f + __expf(-r2));
  float s = w1 + w2; w1 /= s; w2 /= s;
  if (lane == 0) {
    int p = atomicAdd(&cnt[i1], 1); tokens[i1 * T_TOK + p] = t; wts[i1 * T_TOK + p] = w1;
    slotrec[t * 2] = (i1 << 16) | p;
    p = atomicAdd(&cnt[i2], 1);     tokens[i2 * T_TOK + p] = t; wts[i2 * T_TOK + p] = w2;
    slotrec[t * 2 + 1] = (i2 << 16) | p;
  }
}

__global__ void k_fin(const int* __restrict__ cnt, int* __restrict__ base, float* __restrict__ out)
{
  if (threadIdx.x == 0) {
    int b = 0, mx = 0;
    #pragma unroll
    for (int e = 0; e < NE; ++e) { base[e] = b; b += cnt[e]; if (cnt[e] > mx) mx = cnt[e]; }
    base[NE] = b;
    out[(size_t)T_TOK * HD] = (float)mx * (1.f / 1024.f) - 1.f;  // viol
  }
}

// ---------------- fused converts ----------------
__device__ __forceinline__ void tcvt_tile(const float* __restrict__ src, unsigned short* __restrict__ dst,
                                          int K, int N, int mode, int k0, int n0, unsigned short* tl)
{
  const int t = threadIdx.x;
  const int nc = (t & 15) * 4;
  #pragma unroll
  for (int it = 0; it < 4; ++it) {
    int kr = (t >> 4) + it * 16;
    f32x4 v = *(const f32x4*)&src[(size_t)(k0 + kr) * N + n0 + nc];
    #pragma unroll
    for (int j = 0; j < 4; ++j) {
      int n = nc + j;
      tl[n * 64 + (((kr >> 3) ^ (n & 7)) * 8) + (kr & 7)] = f2bf(v[j]);
    }
  }
  __syncthreads();
  #pragma unroll
  for (int it = 0; it < 2; ++it) {
    int idx = t + it * 256;
    int n = idx >> 3, kc8 = idx & 7;
    u32x4 v = *(const u32x4*)&tl[n * 64 + ((kc8 ^ (n & 7)) * 8)];
    int nn = n0 + n;
    int vrow = (mode == 0) ? nn : (((nn >> 5) << 6) + (nn & 31) + ((mode == 2) ? 32 : 0));
    *(u32x4*)&dst[(size_t)vrow * K + k0 + kc8 * 8] = v;
  }
}

// blocks 0..2047: x fp32->bf16; 2048..11263: Wg/Wu/Sg/Su -> Wgu/Sgu; 11264..15871: Wd/Sd -> WdT/SdT
__global__ __launch_bounds__(256) void k_conv(const float* __restrict__ x,
    const float* __restrict__ Wg, const float* __restrict__ Wu,
    const float* __restrict__ Sg, const float* __restrict__ Su,
    const float* __restrict__ Wd, const float* __restrict__ Sd,
    unsigned short* __restrict__ xb, unsigned short* __restrict__ Wgu, unsigned short* __restrict__ Sgu,
    unsigned short* __restrict__ WdT, unsigned short* __restrict__ SdT)
{
  __shared__ __attribute__((aligned(16))) unsigned short tl[64 * 64];
  int bid = blockIdx.x;
  if (bid < 2048) {
    size_t i = ((size_t)bid * 256 + threadIdx.x) * 8;
    f32x4 v0 = *(const f32x4*)(x + i), v1 = *(const f32x4*)(x + i + 4);
    u32x4 pk = { pk2(v0[0],v0[1]), pk2(v0[2],v0[3]), pk2(v1[0],v1[1]), pk2(v1[2],v1[3]) };
    *(u32x4*)&xb[i] = pk;
    return;
  }
  bid -= 2048;
  if (bid < 9216) {
    int z = bid >> 9, rem = bid & 511;
    int bx = rem & 31, by = rem >> 5;
    const float* src; unsigned short* dst; int mode;
    if (z < 8)        { src = Wg + (size_t)z * HD * ID;       dst = Wgu + (size_t)z * 4096 * 1024; mode = 1; }
    else if (z < 16)  { src = Wu + (size_t)(z - 8) * HD * ID; dst = Wgu + (size_t)(z - 8) * 4096 * 1024; mode = 2; }
    else if (z == 16) { src = Sg; dst = Sgu; mode = 1; }
    else              { src = Su; dst = Sgu; mode = 2; }
    tcvt_tile(src, dst, HD, ID, mode, by * 64, bx * 64, tl);
    return;
  }
  bid -= 9216;
  {
    int z = bid >> 9, rem = bid & 511;
    int bx = rem & 15, by = rem >> 4;
    const float* src = (z < 8) ? Wd + (size_t)z * ID * HD : Sd;
    unsigned short* dst = (z < 8) ? WdT + (size_t)z * ID * HD : SdT;
    tcvt_tile(src, dst, ID, HD, 0, by * 64, bx * 64, tl);
  }
}

// bijective chunked XCD mapping over the compacted active-tile list
__device__ __forceinline__ int chunked_vid(int bid, int total) {
  int xcd = bid & 7, idx = bid >> 3;
  int q = total >> 3, r = total & 7;
  int cap = (xcd < r) ? q + 1 : q;
  if (idx >= cap) return -1;
  int base = (xcd < r) ? xcd * (q + 1) : r * (q + 1) + (xcd - r) * q;
  return base + idx;
}

// ================= GEMM1: 256x256 virtual (gate|up interleaved), fat 4-phase =================
__global__ __launch_bounds__(512, 2) void k_mlp1(
    const unsigned short* __restrict__ xb,
    const unsigned short* __restrict__ Wgu, const unsigned short* __restrict__ Sgu,
    const int* __restrict__ cnt, const int* __restrict__ base, const int* __restrict__ tokens,
    unsigned short* __restrict__ act)
{
  __shared__ __attribute__((aligned(16))) unsigned short Abuf[2][16384];
  __shared__ __attribute__((aligned(16))) unsigned short Bbuf[2][16384];

  // compacted active-tile list: vid = pref_e + nx*am_e + my (my fastest -> B-panel adjacency)
  int total = 0;
  #pragma unroll
  for (int ee = 0; ee < 9; ++ee) {
    int c = (ee == 8) ? T_TOK : cnt[ee];
    total += ((c + 255) >> 8) * 16;
  }
  const int vid = chunked_vid(blockIdx.x, total);
  if (vid < 0) return;
  int e = -1, loc = vid, amv = 1;
  #pragma unroll
  for (int ee = 0; ee < 9; ++ee) {
    int c = (ee == 8) ? T_TOK : cnt[ee];
    int a = (c + 255) >> 8;
    int sz = a * 16;
    if (e < 0) { if (loc < sz) { e = ee; amv = a; } else loc -= sz; }
  }
  int nx = 0; while (loc >= amv) { loc -= amv; ++nx; }
  const int my = loc;

  const int cntE = (e == NE) ? T_TOK : cnt[e];
  const int m0 = my * 256;
  const int n0 = nx * 256;
  const unsigned short* Bsrc = (e == NE) ? Sgu : Wgu + (size_t)e * 4096 * 1024;
  const int rowbase = (e == NE) ? 2 * T_TOK : base[e];
  const int tid = threadIdx.x, lane = tid & 63, w = tid >> 6;
  const int srow = tid >> 3;
  const int kgf = (tid & 7) ^ (srow & 7);

  const unsigned short* asrc[4]; const unsigned short* bsrc[4];
  #pragma unroll
  for (int u = 0; u < 4; ++u) {
    int r = u * 64 + srow;
    int rl = min(m0 + r, cntE - 1);
    int tok = (e == NE) ? rl : tokens[e * T_TOK + rl];
    asrc[u] = xb + (size_t)tok * HD + kgf * 8;
    bsrc[u] = Bsrc + (size_t)(n0 + r) * HD + kgf * 8;
  }

  f32x4 acc[8][4];
  const f32x4 z4 = {0.f, 0.f, 0.f, 0.f};
  #pragma unroll
  for (int i = 0; i < 8; ++i)
    #pragma unroll
    for (int j = 0; j < 4; ++j) acc[i][j] = z4;

  const int lr = lane & 15, lg = lane >> 4;
  const int wm = (w >> 2) * 128;
  const int wn4 = (w & 3) * 64;
  const int ck0 = (lg ^ (lr & 7)) * 16;
  const int arow0 = (wm + lr) * 128;
  const int brow0 = (wn4 + lr) * 128;

  bf16x8 af[4][2], bf[2][2][2];

  #define SA1(t_, h_, s_) { \
    gl16(asrc[(h_)*2+0] + (t_)*64, &Abuf[s_][(h_)*8192 + 0    + w*512]); \
    gl16(asrc[(h_)*2+1] + (t_)*64, &Abuf[s_][(h_)*8192 + 4096 + w*512]); }
  #define SB1(t_, h_, s_) { \
    gl16(bsrc[(h_)*2+0] + (t_)*64, &Bbuf[s_][(h_)*8192 + 0    + w*512]); \
    gl16(bsrc[(h_)*2+1] + (t_)*64, &Bbuf[s_][(h_)*8192 + 4096 + w*512]); }
  #define LDA1(s_, mh_) { _Pragma("unroll") for (int am_ = 0; am_ < 4; ++am_) { \
    af[am_][0] = *(const bf16x8*)((const char*)&Abuf[s_][0] + arow0 + (mh_)*8192 + am_*2048 + ck0); \
    af[am_][1] = *(const bf16x8*)((const char*)&Abuf[s_][0] + arow0 + (mh_)*8192 + am_*2048 + (ck0^64)); } }
  #define LDB1(s_, nh_) { _Pragma("unroll") for (int bn_ = 0; bn_ < 2; ++bn_) { \
    bf[nh_][bn_][0] = *(const bf16x8*)((const char*)&Bbuf[s_][0] + brow0 + (nh_)*4096 + bn_*2048 + ck0); \
    bf[nh_][bn_][1] = *(const bf16x8*)((const char*)&Bbuf[s_][0] + brow0 + (nh_)*4096 + bn_*2048 + (ck0^64)); } }
  #define MM1(mh_, nh_) { __builtin_amdgcn_s_setprio(1); \
    _Pragma("unroll") for (int bn_ = 0; bn_ < 2; ++bn_) \
      _Pragma("unroll") for (int am_ = 0; am_ < 4; ++am_) { \
        acc[(mh_)*4+am_][(nh_)*2+bn_] = __builtin_amdgcn_mfma_f32_16x16x32_bf16(af[am_][0], bf[nh_][bn_][0], acc[(mh_)*4+am_][(nh_)*2+bn_], 0,0,0); \
        acc[(mh_)*4+am_][(nh_)*2+bn_] = __builtin_amdgcn_mfma_f32_16x16x32_bf16(af[am_][1], bf[nh_][bn_][1], acc[(mh_)*4+am_][(nh_)*2+bn_], 0,0,0); } \
    __builtin_amdgcn_s_setprio(0); }

  const int NT1 = 16;
  SA1(0, 0, 0); SA1(0, 1, 0); SB1(0, 0, 0); SB1(0, 1, 0);
  SB1(1, 0, 1); SB1(1, 1, 1);
  WAITV(4);
  BAR();

  #define TILE1(t_, s_, o_) { \
    LDA1(s_, 0); LDB1(s_, 0); LDB1(s_, 1); \
    if ((t_)+1 < NT1) { SA1((t_)+1, 0, o_); SA1((t_)+1, 1, o_); } \
    BAR(); LGKM0(); MM1(0, 0); MM1(0, 1); BAR(); \
    LDA1(s_, 1); \
    if ((t_)+2 < NT1) { SB1((t_)+2, 0, s_); SB1((t_)+2, 1, s_); } \
    BAR(); LGKM0(); MM1(1, 1); MM1(1, 0); \
    if ((t_)+2 < NT1) { WAITV(4); } else { WAITV(0); } \
    BAR(); }

  for (int t = 0; t < NT1; t += 2) {
    TILE1(t, 0, 1);
    TILE1(t + 1, 1, 0);
  }
  #undef TILE1

  const int colbase = ((n0 + wn4) >> 1);
  #pragma unroll
  for (int mf = 0; mf < 8; ++mf) {
    const int rloc = wm + (mf >> 2) * 64 + (mf & 3) * 16 + lg * 4;
    #pragma unroll
    for (int p = 0; p < 2; ++p) {
      f32x4 gv = acc[mf][p], uv = acc[mf][p + 2];
      int col = colbase + p * 16 + lr;
      #pragma unroll
      for (int q = 0; q < 4; ++q) {
        int r = rloc + q;
        if (m0 + r < cntE) {
          float g_ = gv[q], u_ = uv[q];
          act[(size_t)(rowbase + m0 + r) * ID + col] = f2bf((g_ / (1.f + __expf(-g_))) * u_);
        }
      }
    }
  }
}

// ================= GEMM2: 256x256, split-K=2, fat 4-phase =================
__global__ __launch_bounds__(512, 2) void k_mlp2(
    const unsigned short* __restrict__ act,
    const unsigned short* __restrict__ WdT, const unsigned short* __restrict__ SdT,
    const int* __restrict__ cnt, const int* __restrict__ base,
    unsigned short* __restrict__ dn0, unsigned short* __restrict__ dn1)
{
  __shared__ __attribute__((aligned(16))) unsigned short Abuf[2][16384];
  __shared__ __attribute__((aligned(16))) unsigned short Bbuf[2][16384];

  // compacted active-tile list: vid = pref_e + (nx*2+kh)*am_e + my
  int total = 0;
  #pragma unroll
  for (int ee = 0; ee < 9; ++ee) {
    int c = (ee == 8) ? T_TOK : cnt[ee];
    total += ((c + 255) >> 8) * 8;
  }
  const int vid = chunked_vid(blockIdx.x, total);
  if (vid < 0) return;
  int e = -1, loc = vid, amv = 1;
  #pragma unroll
  for (int ee = 0; ee < 9; ++ee) {
    int c = (ee == 8) ? T_TOK : cnt[ee];
    int a = (c + 255) >> 8;
    int sz = a * 8;
    if (e < 0) { if (loc < sz) { e = ee; amv = a; } else loc -= sz; }
  }
  int nxkh = 0; while (loc >= amv) { loc -= amv; ++nxkh; }
  const int my = loc;
  const int nx = nxkh >> 1, kh = nxkh & 1;

  const int cntE = (e == NE) ? T_TOK : cnt[e];
  const int m0 = my * 256;
  const int n0 = nx * 256;
  const unsigned short* Bsrc = (e == NE) ? SdT : WdT + (size_t)e * ID * HD;
  const int rowbase = (e == NE) ? 2 * T_TOK : base[e];
  const int koff = kh * 1024;
  const int tid = threadIdx.x, lane = tid & 63, w = tid >> 6;
  const int srow = tid >> 3;
  const int kgf = (tid & 7) ^ (srow & 7);

  const unsigned short* asrc[4]; const unsigned short* bsrc[4];
  #pragma unroll
  for (int u = 0; u < 4; ++u) {
    int r = u * 64 + srow;
    int rl = rowbase + min(m0 + r, cntE - 1);
    asrc[u] = act + (size_t)rl * ID + koff + kgf * 8;
    bsrc[u] = Bsrc + (size_t)(n0 + r) * ID + koff + kgf * 8;
  }

  f32x4 acc[8][4];
  const f32x4 z4 = {0.f, 0.f, 0.f, 0.f};
  #pragma unroll
  for (int i = 0; i < 8; ++i)
    #pragma unroll
    for (int j = 0; j < 4; ++j) acc[i][j] = z4;

  const int lr = lane & 15, lg = lane >> 4;
  const int wm = (w >> 2) * 128;
  const int wn4 = (w & 3) * 64;
  const int ck0 = (lg ^ (lr & 7)) * 16;
  const int arow0 = (wm + lr) * 128;
  const int brow0 = (wn4 + lr) * 128;

  bf16x8 af[4][2], bf[2][2][2];

  #define SA2(t_, h_, s_) { \
    gl16(asrc[(h_)*2+0] + (t_)*64, &Abuf[s_][(h_)*8192 + 0    + w*512]); \
    gl16(asrc[(h_)*2+1] + (t_)*64, &Abuf[s_][(h_)*8192 + 4096 + w*512]); }
  #define SB2(t_, h_, s_) { \
    gl16(bsrc[(h_)*2+0] + (t_)*64, &Bbuf[s_][(h_)*8192 + 0    + w*512]); \
    gl16(bsrc[(h_)*2+1] + (t_)*64, &Bbuf[s_][(h_)*8192 + 4096 + w*512]); }
  #define LDA2(s_, mh_) { _Pragma("unroll") for (int am_ = 0; am_ < 4; ++am_) { \
    af[am_][0] = *(const bf16x8*)((const char*)&Abuf[s_][0] + arow0 + (mh_)*8192 + am_*2048 + ck0); \
    af[am_][1] = *(const bf16x8*)((const char*)&Abuf[s_][0] + arow0 + (mh_)*8192 + am_*2048 + (ck0^64)); } }
  #define LDB2(s_, nh_) { _Pragma("unroll") for (int bn_ = 0; bn_ < 2; ++bn_) { \
    bf[nh_][bn_][0] = *(const bf16x8*)((const char*)&Bbuf[s_][0] + brow0 + (nh_)*4096 + bn_*2048 + ck0); \
    bf[nh_][bn_][1] = *(const bf16x8*)((const char*)&Bbuf[s_][0] + brow0 + (nh_)*4096 + bn_*2048 + (ck0^64)); } }
  #define MM2(mh_, nh_) { __builtin_amdgcn_s_setprio(1); \
    _Pragma("unroll") for (int bn_ = 0; bn_ < 2; ++bn_) \
      _Pragma("unroll") for (int am_ = 0; am_ < 4; ++am_) { \
        acc[(mh_)*4+am_][(nh_)*2+bn_] = __builtin_amdgcn_mfma_f32_16x16x32_bf16(af[am_][0], bf[nh_][bn_][0], acc[(mh_)*4+am_][(nh_)*2+bn_], 0,0,0); \
        acc[(mh_)*4+am_][(nh_)*2+bn_] = __builtin_amdgcn_mfma_f32_16x16x32_bf16(af[am_][1], bf[nh_][bn_][1], acc[(mh_)*4+am_][(nh_)*2+bn_], 0,0,0); } \
    __builtin_amdgcn_s_setprio(0); }

  const int NT2 = 16;
  SA2(0, 0, 0); SA2(0, 1, 0); SB2(0, 0, 0); SB2(0, 1, 0);
  SB2(1, 0, 1); SB2(1, 1, 1);
  WAITV(4);
  BAR();

  #define TILE2(t_, s_, o_) { \
    LDA2(s_, 0); LDB2(s_, 0); LDB2(s_, 1); \
    if ((t_)+1 < NT2) { SA2((t_)+1, 0, o_); SA2((t_)+1, 1, o_); } \
    BAR(); LGKM0(); MM2(0, 0); MM2(0, 1); BAR(); \
    LDA2(s_, 1); \
    if ((t_)+2 < NT2) { SB2((t_)+2, 0, s_); SB2((t_)+2, 1, s_); } \
    BAR(); LGKM0(); MM2(1, 1); MM2(1, 0); \
    if ((t_)+2 < NT2) { WAITV(4); } else { WAITV(0); } \
    BAR(); }

  for (int t = 0; t < NT2; t += 2) {
    TILE2(t, 0, 1);
    TILE2(t + 1, 1, 0);
  }
  #undef TILE2
  #undef SA2
  #undef SB2
  #undef LDA2
  #undef LDB2
  #undef MM2

  unsigned short* dnp = kh ? dn1 : dn0;
  #pragma unroll
  for (int mf = 0; mf < 8; ++mf) {
    const int rloc = wm + (mf >> 2) * 64 + (mf & 3) * 16 + lg * 4;
    #pragma unroll
    for (int nf = 0; nf < 4; ++nf) {
      f32x4 av = acc[mf][nf];
      int col = n0 + wn4 + nf * 16 + lr;
      #pragma unroll
      for (int q = 0; q < 4; ++q) {
        int r = rloc + q;
        if (m0 + r < cntE)
          dnp[(size_t)(rowbase + m0 + r) * HD + col] = f2bf(av[q]);
      }
    }
  }
}

// ---------------- combine ----------------
__global__ __launch_bounds__(256) void k_comb(const unsigned short* __restrict__ dn0,
    const unsigned short* __restrict__ dn1,
    const int* __restrict__ base, const int* __restrict__ slotrec,
    const float* __restrict__ wts, float* __restrict__ out)
{
  const int t = blockIdx.x;
  const int c = threadIdx.x * 4;
  int r0 = slotrec[t * 2], r1 = slotrec[t * 2 + 1];
  int e0 = r0 >> 16, p0 = r0 & 0xffff;
  int e1 = r1 >> 16, p1 = r1 & 0xffff;
  size_t s0 = (size_t)(base[e0] + p0) * HD + c;
  size_t s1 = (size_t)(base[e1] + p1) * HD + c;
  size_t sh = (size_t)(2 * T_TOK + t) * HD + c;
  float w0 = wts[e0 * T_TOK + p0], w1 = wts[e1 * T_TOK + p1];
  u32x2 vs0 = *(const u32x2*)&dn0[sh], vs1 = *(const u32x2*)&dn1[sh];
  u32x2 va0 = *(const u32x2*)&dn0[s0], va1 = *(const u32x2*)&dn1[s0];
  u32x2 vb0 = *(const u32x2*)&dn0[s1], vb1 = *(const u32x2*)&dn1[s1];
  f32x4 o;
  o[0] = (bflo(vs0[0]) + bflo(vs1[0])) + w0 * (bflo(va0[0]) + bflo(va1[0])) + w1 * (bflo(vb0[0]) + bflo(vb1[0]));
  o[1] = (bfhi(vs0[0]) + bfhi(vs1[0])) + w0 * (bfhi(va0[0]) + bfhi(va1[0])) + w1 * (bfhi(vb0[0]) + bfhi(vb1[0]));
  o[2] = (bflo(vs0[1]) + bflo(vs1[1])) + w0 * (bflo(va0[1]) + bflo(va1[1])) + w1 * (bflo(vb0[1]) + bflo(vb1[1]));
  o[3] = (bfhi(vs0[1]) + bfhi(vs1[1])) + w0 * (bfhi(va0[1]) + bfhi(va1[1])) + w1 * (bfhi(vb0[1]) + bfhi(vb1[1]));
  *(f32x4*)&out[(size_t)t * HD + c] = o;
}

extern "C" void kernel_launch(void* const* d_in, const int* in_sizes, int n_in,
                              void* d_out, int out_size, void* d_ws, size_t ws_size,
                              hipStream_t stream)
{
  const float* x    = (const float*)d_in[0];
  const float* gw   = (const float*)d_in[1];
  const float* bias = (const float*)d_in[2];
  const float* Wg   = (const float*)d_in[3];
  const float* Wu   = (const float*)d_in[4];
  const float* Wd   = (const float*)d_in[5];
  const float* Sg   = (const float*)d_in[6];
  const float* Su   = (const float*)d_in[7];
  const float* Sd   = (const float*)d_in[8];
  float* out = (float*)d_out;
  char* ws = (char*)d_ws;

  int*   cnt     = (int*)ws;
  int*   base    = cnt + 16;
  int*   tokens  = (int*)(ws + 512);
  float* wts     = (float*)(ws + 512 + (NE * T_TOK * 4));
  int*   slotrec = (int*)(ws + 512 + 2 * (NE * T_TOK * 4));

  const size_t MB = (size_t)1 << 20;
  unsigned short* xbf = (unsigned short*)(ws + 1 * MB);    // 8 MB
  unsigned short* WdT = (unsigned short*)(ws + 9 * MB);    // 32 MB
  unsigned short* SdT = (unsigned short*)(ws + 41 * MB);   // 4 MB
  unsigned short* Wgu = (unsigned short*)(ws + 45 * MB);   // 64 MB (dead after mlp1)
  unsigned short* Sgu = (unsigned short*)(ws + 109 * MB);  // 8 MB (dead after mlp1)
  unsigned short* actb = (unsigned short*)(ws + 117 * MB); // 48 MB
  unsigned short* dn0 = (unsigned short*)(ws + 45 * MB);   // 24 MB, overlays Wgu
  unsigned short* dn1 = (unsigned short*)(ws + 69 * MB);   // 24 MB, overlays Wgu

  k_zero<<<dim3(1), dim3(64), 0, stream>>>(cnt);
  k_route<<<dim3(T_TOK / 4), dim3(256), 0, stream>>>(x, gw, bias, cnt, tokens, wts, slotrec);
  k_fin<<<dim3(1), dim3(64), 0, stream>>>(cnt, base, out);
  k_conv<<<dim3(2048 + 9216 + 4608), dim3(256), 0, stream>>>(x, Wg, Wu, Sg, Su, Wd, Sd,
                                                             xbf, Wgu, Sgu, WdT, SdT);
  k_mlp1<<<dim3(2304), dim3(512), 0, stream>>>(xbf, Wgu, Sgu, cnt, base, tokens, actb);
  k_mlp2<<<dim3(1152), dim3(512), 0, stream>>>(actb, WdT, SdT, cnt, base, dn0, dn1);
  k_comb<<<dim3(T_TOK), dim3(256), 0, stream>>>(dn0, dn1, base, slotrec, wts, out);
}